// Round 3
// baseline (236.149 us; speedup 1.0000x reference)
//
#include <hip/hip_runtime.h>

// MHA fused forward for B=4,T=2048,E=1024,H=16,D=64 on gfx950.
// prep (bf16 cast + weight transpose, QK-scale folded into Wq) -> GEMM1 (QKV) -> flash attn
// (32x32 MFMA, T12 cvt_pk+permlane32_swap softmax) -> GEMM2 (out proj).

typedef __attribute__((ext_vector_type(8))) __bf16 bf16x8;
typedef __attribute__((ext_vector_type(4))) float f32x4;
typedef __attribute__((ext_vector_type(16))) float f32x16;
typedef __attribute__((ext_vector_type(4))) unsigned int u32x4;
typedef __attribute__((ext_vector_type(2))) unsigned int u32x2;
typedef unsigned short u16;
typedef unsigned int u32;

#define DEV __device__ __forceinline__

#define QK_SCALE 0.18033688011112042f   // 0.125 * log2(e) : folded into Wq/bq

DEV u16 f2bf(float f) {          // round-to-nearest-even f32 -> bf16 (inputs never NaN)
  u32 u = __builtin_bit_cast(u32, f);
  u += 0x7fffu + ((u >> 16) & 1u);
  return (u16)(u >> 16);
}
DEV u32 pack2(float a, float b) { return (u32)f2bf(a) | ((u32)f2bf(b) << 16); }

DEV float exp2_hw(float x) { float r; asm("v_exp_f32 %0, %1" : "=v"(r) : "v"(x)); return r; }
DEV u32 cvtpk_bf16(float lo, float hi) {
  u32 r; asm("v_cvt_pk_bf16_f32 %0, %1, %2" : "=v"(r) : "v"(lo), "v"(hi)); return r;
}
DEV void pl32swap(u32& a, u32& b) { asm("v_permlane32_swap_b32 %0, %1" : "+v"(a), "+v"(b)); }

DEV f32x16 zero16() { f32x16 z;
#pragma unroll
  for (int i = 0; i < 16; i++) z[i] = 0.f;
  return z; }

// ---------------------------------------------------------------- prep: x->bf16, bias concat
__global__ __launch_bounds__(256) void prep_x_kernel(
    const float* __restrict__ x, const float* __restrict__ bq, const float* __restrict__ bk,
    const float* __restrict__ bv, u16* __restrict__ xbf, float* __restrict__ bqkv) {
  int gid = blockIdx.x * 256 + threadIdx.x;
  if (gid < 3072) {
    float v = (gid < 1024) ? bq[gid] * QK_SCALE : (gid < 2048 ? bk[gid - 1024] : bv[gid - 2048]);
    bqkv[gid] = v;
  }
  const float4* xv = (const float4*)x;
  float4 f0 = xv[(size_t)gid * 2];
  float4 f1 = xv[(size_t)gid * 2 + 1];
  u32x4 st;
  st.x = pack2(f0.x, f0.y); st.y = pack2(f0.z, f0.w);
  st.z = pack2(f1.x, f1.y); st.w = pack2(f1.z, f1.w);
  *(u32x4*)&xbf[(size_t)gid * 8] = st;
}

// ---------------------------------------------------------------- prep: weight transposes to B^T bf16
__global__ __launch_bounds__(256) void prep_w_kernel(
    const float* __restrict__ Wq, const float* __restrict__ Wk, const float* __restrict__ Wv,
    const float* __restrict__ Wp, u16* __restrict__ wqkvT, u16* __restrict__ wpT) {
  __shared__ float t[64][65];
  int bid = blockIdx.x, tid = threadIdx.x;
  int r0 = tid >> 6, c = tid & 63;
  if (bid < 768) {
    int p = bid >> 8, rem = bid & 255, h = rem >> 4, et = rem & 15;
    float sc = (p == 0) ? QK_SCALE : 1.0f;
    const float* src = (p == 0 ? Wq : (p == 1 ? Wk : Wv)) + ((size_t)h * 1024 + et * 64) * 64;
#pragma unroll
    for (int i = 0; i < 16; i++) { int e = r0 + i * 4; t[e][c] = src[(size_t)e * 64 + c]; }
    __syncthreads();
    u16* dst = wqkvT + ((size_t)p * 1024 + h * 64) * 1024 + et * 64;
#pragma unroll
    for (int i = 0; i < 16; i++) { int d = r0 + i * 4; dst[(size_t)d * 1024 + c] = f2bf(t[c][d] * sc); }
  } else {
    int b2 = bid - 768, rt = b2 >> 4, ct = b2 & 15;
#pragma unroll
    for (int i = 0; i < 16; i++) { int e = r0 + i * 4; t[e][c] = Wp[(size_t)(rt * 64 + e) * 1024 + ct * 64 + c]; }
    __syncthreads();
#pragma unroll
    for (int i = 0; i < 16; i++) { int f = r0 + i * 4; wpT[(size_t)(ct * 64 + f) * 1024 + rt * 64 + c] = f2bf(t[c][f]); }
  }
}

// ---------------------------------------------------------------- GEMM 128x128 tile, K=1024, BK=64
DEV void stage_tile(const u16* __restrict__ X, int row0, int k0, u16* lds, int tid) {
#pragma unroll
  for (int j = 0; j < 4; j++) {
    int ci = j * 256 + tid;
    int row = ci >> 3, slot = ci & 7;
    int srcslot = slot ^ (row & 7);
    const u16* gp = X + (size_t)(row0 + row) * 1024 + k0 + srcslot * 8;
    __builtin_amdgcn_global_load_lds((const __attribute__((address_space(1))) void*)gp,
                                     (__attribute__((address_space(3))) void*)(lds + ci * 8),
                                     16, 0, 0);
  }
}

__global__ __launch_bounds__(256) void gemm128_kernel(
    const u16* __restrict__ A, const u16* __restrict__ Bt, const float* __restrict__ bias,
    int tilesN, int mode, u16* __restrict__ Qb, u16* __restrict__ Kb, u16* __restrict__ VTb,
    float* __restrict__ outF) {
  __shared__ u16 As[128 * 64];
  __shared__ u16 Bs[128 * 64];
  int nwg = gridDim.x;
  int bid = blockIdx.x;
  int swz = (bid % 8) * (nwg / 8) + bid / 8;
  int bm = swz / tilesN, bn = swz % tilesN;
  int tid = threadIdx.x;
  int lane = tid & 63, wave = tid >> 6;
  int wm = wave >> 1, wn = wave & 1;
  int lr = lane & 15, lg = lane >> 4;

  f32x4 acc[4][4];
#pragma unroll
  for (int i = 0; i < 4; i++)
#pragma unroll
    for (int j = 0; j < 4; j++) acc[i][j] = f32x4{0.f, 0.f, 0.f, 0.f};

  for (int k0 = 0; k0 < 1024; k0 += 64) {
    stage_tile(A, bm * 128, k0, As, tid);
    stage_tile(Bt, bn * 128, k0, Bs, tid);
    __syncthreads();
#pragma unroll
    for (int kf = 0; kf < 2; kf++) {
      bf16x8 af[4], bfr[4];
#pragma unroll
      for (int i = 0; i < 4; i++) {
        int ra = wm * 64 + i * 16 + lr;
        af[i] = *(const bf16x8*)&As[ra * 64 + (((lg + kf * 4) ^ (ra & 7)) * 8)];
        int rb = wn * 64 + i * 16 + lr;
        bfr[i] = *(const bf16x8*)&Bs[rb * 64 + (((lg + kf * 4) ^ (rb & 7)) * 8)];
      }
      __builtin_amdgcn_s_setprio(1);
#pragma unroll
      for (int i = 0; i < 4; i++)
#pragma unroll
        for (int j = 0; j < 4; j++)
          acc[i][j] = __builtin_amdgcn_mfma_f32_16x16x32_bf16(af[i], bfr[j], acc[i][j], 0, 0, 0);
      __builtin_amdgcn_s_setprio(0);
    }
    __syncthreads();
  }

  int crow = bm * 128 + wm * 64;
  int ccol = bn * 128 + wn * 64;
  if (mode == 0) {
#pragma unroll
    for (int j = 0; j < 4; j++) {
      int col = ccol + j * 16 + lr;
      float bb = bias[col];
      int p = col >> 10, h = (col >> 6) & 15, d = col & 63;
#pragma unroll
      for (int i = 0; i < 4; i++) {
        int row0 = crow + i * 16 + lg * 4;
        int b_ = row0 >> 11, t0 = row0 & 2047;
        if (p == 2) {
          u32x2 pv;
          pv.x = pack2(acc[i][j][0] + bb, acc[i][j][1] + bb);
          pv.y = pack2(acc[i][j][2] + bb, acc[i][j][3] + bb);
          *(u32x2*)&VTb[((size_t)(b_ * 16 + h) * 64 + d) * 2048 + t0] = pv;
        } else {
          u16* dst = (p == 0 ? Qb : Kb);
#pragma unroll
          for (int r = 0; r < 4; r++)
            dst[((size_t)(b_ * 16 + h) * 2048 + (t0 + r)) * 64 + d] = f2bf(acc[i][j][r] + bb);
        }
      }
    }
  } else {
#pragma unroll
    for (int j = 0; j < 4; j++) {
      int col = ccol + j * 16 + lr;
      float bb = bias[col];
#pragma unroll
      for (int i = 0; i < 4; i++) {
        int row0 = crow + i * 16 + lg * 4;
#pragma unroll
        for (int r = 0; r < 4; r++)
          outF[(size_t)(row0 + r) * 1024 + col] = acc[i][j][r] + bb;
      }
    }
  }
}

// ---------------------------------------------------------------- flash attention (causal, 32x32)
// Block = 4 waves; wave owns 32 q-rows of ctxA (q-tile p) and 32 of ctxB (q-tile 15-p):
// uniform causal work. K/V double-buffered in LDS (XOR swizzle both sides). Swapped QK^T
// (S^T = K·Q^T) makes kv-reduction in-lane; P->B-frag via cvt_pk + permlane32_swap (T12).
struct BTrue  { static constexpr bool value = true;  };
struct BFalse { static constexpr bool value = false; };

DEV void stage_kv(const u16* __restrict__ Kh, const u16* __restrict__ Vh, int kv0,
                  u16* Ksb, u16* Vsb, int tid) {
#pragma unroll
  for (int j = 0; j < 2; j++) {
    int ci = j * 256 + tid;                 // 512 chunks of 16B = 64 rows x 8 slots
    int row = ci >> 3, slot = ci & 7;
    int ss = slot ^ (row & 7);
    __builtin_amdgcn_global_load_lds(
        (const __attribute__((address_space(1))) void*)(Kh + (size_t)(kv0 + row) * 64 + ss * 8),
        (__attribute__((address_space(3))) void*)(Ksb + ci * 8), 16, 0, 0);
    __builtin_amdgcn_global_load_lds(
        (const __attribute__((address_space(1))) void*)(Vh + (size_t)row * 2048 + kv0 + ss * 8),
        (__attribute__((address_space(3))) void*)(Vsb + ci * 8), 16, 0, 0);
  }
}

// online softmax over one 64kv x 32q S^T tile held as s[2] (f32x16 each); exp2 domain.
DEV void softmax32(f32x16 s[2], float& m_run, float& l_run, f32x16& o0, f32x16& o1,
                   bool needmask, int kv0, int qg, int hi) {
  if (needmask) {
#pragma unroll
    for (int blk = 0; blk < 2; blk++)
#pragma unroll
      for (int r = 0; r < 16; r++) {
        int kv = kv0 + blk * 32 + (r & 3) + 8 * (r >> 2) + 4 * hi;
        if (kv > qg) s[blk][r] = -1e30f;
      }
  }
  float tm0 = -1e30f, tm1 = -1e30f, tm2 = -1e30f, tm3 = -1e30f;
#pragma unroll
  for (int blk = 0; blk < 2; blk++)
#pragma unroll
    for (int j = 0; j < 4; j++) {
      tm0 = fmaxf(tm0, s[blk][j * 4 + 0]); tm1 = fmaxf(tm1, s[blk][j * 4 + 1]);
      tm2 = fmaxf(tm2, s[blk][j * 4 + 2]); tm3 = fmaxf(tm3, s[blk][j * 4 + 3]);
    }
  float tmax = fmaxf(fmaxf(tm0, tm1), fmaxf(tm2, tm3));
  tmax = fmaxf(tmax, __shfl_xor(tmax, 32));
  float m_new = fmaxf(m_run, tmax);
  float corr = exp2_hw(m_run - m_new);
  m_run = m_new;
  float t0 = 0.f, t1 = 0.f, t2 = 0.f, t3 = 0.f;
#pragma unroll
  for (int blk = 0; blk < 2; blk++)
#pragma unroll
    for (int j = 0; j < 4; j++) {
      float p0 = exp2_hw(s[blk][j * 4 + 0] - m_new); s[blk][j * 4 + 0] = p0; t0 += p0;
      float p1 = exp2_hw(s[blk][j * 4 + 1] - m_new); s[blk][j * 4 + 1] = p1; t1 += p1;
      float p2 = exp2_hw(s[blk][j * 4 + 2] - m_new); s[blk][j * 4 + 2] = p2; t2 += p2;
      float p3 = exp2_hw(s[blk][j * 4 + 3] - m_new); s[blk][j * 4 + 3] = p3; t3 += p3;
    }
  float ts = (t0 + t1) + (t2 + t3);
  ts += __shfl_xor(ts, 32);
  l_run = l_run * corr + ts;
  o0 = o0 * corr;
  o1 = o1 * corr;
}

// P^T (C-layout, 32 values) -> 4 PV B-operand fragments. For frag ks (K=16 kv-slice):
// words = [swapA.a, swapB.a, swapA.b, swapB.b] of swap(pk[m0],pk[m0+2]), swap(pk[m0+1],pk[m0+3]).
DEV void build_pf(const f32x16 s[2], bf16x8 pf[4]) {
  u32 pk[2][8];
#pragma unroll
  for (int blk = 0; blk < 2; blk++)
#pragma unroll
    for (int m = 0; m < 8; m++) pk[blk][m] = cvtpk_bf16(s[blk][2 * m], s[blk][2 * m + 1]);
#pragma unroll
  for (int ks = 0; ks < 4; ks++) {
    int blk = ks >> 1, g = (ks & 1) * 4;
    u32 a = pk[blk][g + 0], b = pk[blk][g + 2];
    u32 c = pk[blk][g + 1], d = pk[blk][g + 3];
    pl32swap(a, b);
    pl32swap(c, d);
    u32x4 w; w.x = a; w.y = c; w.z = b; w.w = d;
    pf[ks] = __builtin_bit_cast(bf16x8, w);
  }
}

__global__ __launch_bounds__(256) void attn_kernel(
    const u16* __restrict__ Qb, const u16* __restrict__ Kb, const u16* __restrict__ VTb,
    u16* __restrict__ cat) {
  __shared__ u16 Ks[2][64 * 64];
  __shared__ u16 Vs[2][64 * 64];
  int bid = blockIdx.x;                       // 512 = 64 bh x 8 pairs
  int swz = (bid & 7) * 64 + (bid >> 3);      // 64 consecutive per XCD: 8 heads/XCD
  int bh = swz >> 3, p = swz & 7;
  int qa = p, qb = 15 - p;                    // 128-row q-tiles
  int b = bh >> 4, h = bh & 15;
  int tid = threadIdx.x, wave = tid >> 6, lane = tid & 63;
  int l31 = lane & 31, hi = lane >> 5;

  const u16* Qh = Qb + (size_t)bh * 2048 * 64;
  const u16* Kh = Kb + (size_t)bh * 2048 * 64;
  const u16* Vh = VTb + (size_t)bh * 64 * 2048;

  int q0a = qa * 128 + wave * 32;
  int q0b = qb * 128 + wave * 32;
  int qga = q0a + l31, qgb = q0b + l31;

  bf16x8 qfA[4], qfB[4];     // B-operand: col=q (lane&31), k = ks*16 + hi*8 + i
#pragma unroll
  for (int ks = 0; ks < 4; ks++) {
    qfA[ks] = *(const bf16x8*)&Qh[(size_t)qga * 64 + ks * 16 + hi * 8];
    qfB[ks] = *(const bf16x8*)&Qh[(size_t)qgb * 64 + ks * 16 + hi * 8];
  }

  f32x16 oA[2], oB[2];
  oA[0] = zero16(); oA[1] = zero16(); oB[0] = zero16(); oB[1] = zero16();
  float mA = -1e30f, lA = 0.f, mB = -1e30f, lB = 0.f;

  stage_kv(Kh, Vh, 0, Ks[0], Vs[0], tid);
  __syncthreads();
  int cur = 0;
  int lastA = 2 * qa + 1, lastB = 2 * qb + 1;

  for (int kvt = 0; kvt <= lastB; ++kvt) {
    int kv0 = kvt * 64;
    if (kvt < lastB) stage_kv(Kh, Vh, kv0 + 64, Ks[cur ^ 1], Vs[cur ^ 1], tid);

    auto tile_body = [&](auto actc) {
      constexpr bool ACT = decltype(actc)::value;
      f32x16 sA[2], sB[2];
      sB[0] = zero16(); sB[1] = zero16();
      if (ACT) { sA[0] = zero16(); sA[1] = zero16(); }
      // QK^T : S^T[kv][q], K-frags shared across contexts
      __builtin_amdgcn_s_setprio(1);
#pragma unroll
      for (int blk = 0; blk < 2; blk++)
#pragma unroll
        for (int ks = 0; ks < 4; ks++) {
          int row = blk * 32 + l31;
          bf16x8 kf = *(const bf16x8*)&Ks[cur][row * 64 + (((ks * 2 + hi) ^ (row & 7)) * 8)];
          sB[blk] = __builtin_amdgcn_mfma_f32_32x32x16_bf16(kf, qfB[ks], sB[blk], 0, 0, 0);
          if (ACT) sA[blk] = __builtin_amdgcn_mfma_f32_32x32x16_bf16(kf, qfA[ks], sA[blk], 0, 0, 0);
        }
      __builtin_amdgcn_s_setprio(0);

      bf16x8 pfB[4], pfA[4];
      softmax32(sB, mB, lB, oB[0], oB[1], kv0 + 63 > q0b, kv0, qgb, hi);
      build_pf(sB, pfB);
      if (ACT) {
        softmax32(sA, mA, lA, oA[0], oA[1], kv0 + 63 > q0a, kv0, qga, hi);
        build_pf(sA, pfA);
      }
      // PV : O^T[d][q], V-frags shared across contexts
      __builtin_amdgcn_s_setprio(1);
#pragma unroll
      for (int dblk = 0; dblk < 2; dblk++)
#pragma unroll
        for (int ks = 0; ks < 4; ks++) {
          int row = dblk * 32 + l31;
          bf16x8 vf = *(const bf16x8*)&Vs[cur][row * 64 + (((ks * 2 + hi) ^ (row & 7)) * 8)];
          oB[dblk] = __builtin_amdgcn_mfma_f32_32x32x16_bf16(vf, pfB[ks], oB[dblk], 0, 0, 0);
          if (ACT) oA[dblk] = __builtin_amdgcn_mfma_f32_32x32x16_bf16(vf, pfA[ks], oA[dblk], 0, 0, 0);
        }
      __builtin_amdgcn_s_setprio(0);
    };
    if (kvt <= lastA) tile_body(BTrue{}); else tile_body(BFalse{});

    __syncthreads();
    cur ^= 1;
  }

  float liA = 1.0f / lA, liB = 1.0f / lB;
#pragma unroll
  for (int dblk = 0; dblk < 2; dblk++)
#pragma unroll
    for (int m = 0; m < 8; m++) {
      int dbase = dblk * 32 + 2 * (m & 1) + 8 * (m >> 1) + 4 * hi;
      u32 wa = cvtpk_bf16(oA[dblk][2 * m] * liA, oA[dblk][2 * m + 1] * liA);
      u32 wb = cvtpk_bf16(oB[dblk][2 * m] * liB, oB[dblk][2 * m + 1] * liB);
      *(u32*)&cat[(size_t)(b * 2048 + qga) * 1024 + h * 64 + dbase] = wa;
      *(u32*)&cat[(size_t)(b * 2048 + qgb) * 1024 + h * 64 + dbase] = wb;
    }
}

// ---------------------------------------------------------------- launch
extern "C" void kernel_launch(void* const* d_in, const int* in_sizes, int n_in,
                              void* d_out, int out_size, void* d_ws, size_t ws_size,
                              hipStream_t stream) {
  const float* x  = (const float*)d_in[0];
  const float* Wq = (const float*)d_in[1];
  const float* bq = (const float*)d_in[2];
  const float* Wk = (const float*)d_in[3];
  const float* bk = (const float*)d_in[4];
  const float* Wv = (const float*)d_in[5];
  const float* bv = (const float*)d_in[6];
  const float* Wp = (const float*)d_in[7];
  const float* bp = (const float*)d_in[8];

  char* w = (char*)d_ws;
  u16* xbf    = (u16*)w;                 w += (size_t)8192 * 1024 * 2;
  u16* wqkvT  = (u16*)w;                 w += (size_t)3072 * 1024 * 2;
  u16* wpT    = (u16*)w;                 w += (size_t)1024 * 1024 * 2;
  float* bqkv = (float*)w;               w += (size_t)3072 * 4;
  u16* Qb     = (u16*)w;                 w += (size_t)64 * 2048 * 64 * 2;
  u16* Kb     = (u16*)w;                 w += (size_t)64 * 2048 * 64 * 2;
  u16* VTb    = (u16*)w;                 w += (size_t)64 * 64 * 2048 * 2;
  u16* cat    = (u16*)w;                 w += (size_t)8192 * 1024 * 2;

  prep_x_kernel<<<4096, 256, 0, stream>>>(x, bq, bk, bv, xbf, bqkv);
  prep_w_kernel<<<1024, 256, 0, stream>>>(Wq, Wk, Wv, Wp, wqkvT, wpT);
  gemm128_kernel<<<1536, 256, 0, stream>>>(xbf, wqkvT, bqkv, 24, 0, Qb, Kb, VTb, nullptr);
  attn_kernel<<<512, 256, 0, stream>>>(Qb, Kb, VTb, cat);
  gemm128_kernel<<<512, 256, 0, stream>>>(cat, wpT, bp, 8, 1, nullptr, nullptr, nullptr, (float*)d_out);
}

// Round 4
// 181.812 us; speedup vs baseline: 1.2989x; 1.2989x over previous
//
#include <hip/hip_runtime.h>

// MHA fused forward for B=4,T=2048,E=1024,H=16,D=64 on gfx950.
// prep (bf16 cast + weight transpose, QK-scale folded into Wq) -> GEMM1 (QKV) -> flash attn
// (32x32 MFMA, column-split causal pairing, T12 cvt_pk+permlane32_swap) -> GEMM2 (out proj).

typedef __attribute__((ext_vector_type(8))) __bf16 bf16x8;
typedef __attribute__((ext_vector_type(4))) float f32x4;
typedef __attribute__((ext_vector_type(16))) float f32x16;
typedef __attribute__((ext_vector_type(4))) unsigned int u32x4;
typedef __attribute__((ext_vector_type(2))) unsigned int u32x2;
typedef unsigned short u16;
typedef unsigned int u32;

#define DEV __device__ __forceinline__

#define QK_SCALE 0.18033688011112042f   // 0.125 * log2(e) : folded into Wq/bq

DEV u16 f2bf(float f) {          // round-to-nearest-even f32 -> bf16 (inputs never NaN)
  u32 u = __builtin_bit_cast(u32, f);
  u += 0x7fffu + ((u >> 16) & 1u);
  return (u16)(u >> 16);
}
DEV u32 pack2(float a, float b) { return (u32)f2bf(a) | ((u32)f2bf(b) << 16); }

DEV float exp2_hw(float x) { float r; asm("v_exp_f32 %0, %1" : "=v"(r) : "v"(x)); return r; }
DEV u32 cvtpk_bf16(float lo, float hi) {
  u32 r; asm("v_cvt_pk_bf16_f32 %0, %1, %2" : "=v"(r) : "v"(lo), "v"(hi)); return r;
}
DEV void pl32swap(u32& a, u32& b) { asm("v_permlane32_swap_b32 %0, %1" : "+v"(a), "+v"(b)); }

DEV f32x16 zero16() { f32x16 z;
#pragma unroll
  for (int i = 0; i < 16; i++) z[i] = 0.f;
  return z; }

// ---------------------------------------------------------------- prep: x->bf16, bias concat
__global__ __launch_bounds__(256) void prep_x_kernel(
    const float* __restrict__ x, const float* __restrict__ bq, const float* __restrict__ bk,
    const float* __restrict__ bv, u16* __restrict__ xbf, float* __restrict__ bqkv) {
  int gid = blockIdx.x * 256 + threadIdx.x;
  if (gid < 3072) {
    float v = (gid < 1024) ? bq[gid] * QK_SCALE : (gid < 2048 ? bk[gid - 1024] : bv[gid - 2048]);
    bqkv[gid] = v;
  }
  const float4* xv = (const float4*)x;
  float4 f0 = xv[(size_t)gid * 2];
  float4 f1 = xv[(size_t)gid * 2 + 1];
  u32x4 st;
  st.x = pack2(f0.x, f0.y); st.y = pack2(f0.z, f0.w);
  st.z = pack2(f1.x, f1.y); st.w = pack2(f1.z, f1.w);
  *(u32x4*)&xbf[(size_t)gid * 8] = st;
}

// ---------------------------------------------------------------- prep: weight transposes to B^T bf16
__global__ __launch_bounds__(256) void prep_w_kernel(
    const float* __restrict__ Wq, const float* __restrict__ Wk, const float* __restrict__ Wv,
    const float* __restrict__ Wp, u16* __restrict__ wqkvT, u16* __restrict__ wpT) {
  __shared__ float t[64][65];
  int bid = blockIdx.x, tid = threadIdx.x;
  int r0 = tid >> 6, c = tid & 63;
  if (bid < 768) {
    int p = bid >> 8, rem = bid & 255, h = rem >> 4, et = rem & 15;
    float sc = (p == 0) ? QK_SCALE : 1.0f;
    const float* src = (p == 0 ? Wq : (p == 1 ? Wk : Wv)) + ((size_t)h * 1024 + et * 64) * 64;
#pragma unroll
    for (int i = 0; i < 16; i++) { int e = r0 + i * 4; t[e][c] = src[(size_t)e * 64 + c]; }
    __syncthreads();
    u16* dst = wqkvT + ((size_t)p * 1024 + h * 64) * 1024 + et * 64;
#pragma unroll
    for (int i = 0; i < 16; i++) { int d = r0 + i * 4; dst[(size_t)d * 1024 + c] = f2bf(t[c][d] * sc); }
  } else {
    int b2 = bid - 768, rt = b2 >> 4, ct = b2 & 15;
#pragma unroll
    for (int i = 0; i < 16; i++) { int e = r0 + i * 4; t[e][c] = Wp[(size_t)(rt * 64 + e) * 1024 + ct * 64 + c]; }
    __syncthreads();
#pragma unroll
    for (int i = 0; i < 16; i++) { int f = r0 + i * 4; wpT[(size_t)(ct * 64 + f) * 1024 + rt * 64 + c] = f2bf(t[c][f]); }
  }
}

// ---------------------------------------------------------------- GEMM 128x128 tile, K=1024, BK=64
DEV void stage_tile(const u16* __restrict__ X, int row0, int k0, u16* lds, int tid) {
#pragma unroll
  for (int j = 0; j < 4; j++) {
    int ci = j * 256 + tid;
    int row = ci >> 3, slot = ci & 7;
    int srcslot = slot ^ (row & 7);
    const u16* gp = X + (size_t)(row0 + row) * 1024 + k0 + srcslot * 8;
    __builtin_amdgcn_global_load_lds((const __attribute__((address_space(1))) void*)gp,
                                     (__attribute__((address_space(3))) void*)(lds + ci * 8),
                                     16, 0, 0);
  }
}

__global__ __launch_bounds__(256) void gemm128_kernel(
    const u16* __restrict__ A, const u16* __restrict__ Bt, const float* __restrict__ bias,
    int tilesN, int mode, u16* __restrict__ Qb, u16* __restrict__ Kb, u16* __restrict__ VTb,
    float* __restrict__ outF) {
  __shared__ u16 As[128 * 64];
  __shared__ u16 Bs[128 * 64];
  int nwg = gridDim.x;
  int bid = blockIdx.x;
  int swz = (bid % 8) * (nwg / 8) + bid / 8;
  int bm = swz / tilesN, bn = swz % tilesN;
  int tid = threadIdx.x;
  int lane = tid & 63, wave = tid >> 6;
  int wm = wave >> 1, wn = wave & 1;
  int lr = lane & 15, lg = lane >> 4;

  f32x4 acc[4][4];
#pragma unroll
  for (int i = 0; i < 4; i++)
#pragma unroll
    for (int j = 0; j < 4; j++) acc[i][j] = f32x4{0.f, 0.f, 0.f, 0.f};

  for (int k0 = 0; k0 < 1024; k0 += 64) {
    stage_tile(A, bm * 128, k0, As, tid);
    stage_tile(Bt, bn * 128, k0, Bs, tid);
    __syncthreads();
#pragma unroll
    for (int kf = 0; kf < 2; kf++) {
      bf16x8 af[4], bfr[4];
#pragma unroll
      for (int i = 0; i < 4; i++) {
        int ra = wm * 64 + i * 16 + lr;
        af[i] = *(const bf16x8*)&As[ra * 64 + (((lg + kf * 4) ^ (ra & 7)) * 8)];
        int rb = wn * 64 + i * 16 + lr;
        bfr[i] = *(const bf16x8*)&Bs[rb * 64 + (((lg + kf * 4) ^ (rb & 7)) * 8)];
      }
      __builtin_amdgcn_s_setprio(1);
#pragma unroll
      for (int i = 0; i < 4; i++)
#pragma unroll
        for (int j = 0; j < 4; j++)
          acc[i][j] = __builtin_amdgcn_mfma_f32_16x16x32_bf16(af[i], bfr[j], acc[i][j], 0, 0, 0);
      __builtin_amdgcn_s_setprio(0);
    }
    __syncthreads();
  }

  int crow = bm * 128 + wm * 64;
  int ccol = bn * 128 + wn * 64;
  if (mode == 0) {
#pragma unroll
    for (int j = 0; j < 4; j++) {
      int col = ccol + j * 16 + lr;
      float bb = bias[col];
      int p = col >> 10, h = (col >> 6) & 15, d = col & 63;
#pragma unroll
      for (int i = 0; i < 4; i++) {
        int row0 = crow + i * 16 + lg * 4;
        int b_ = row0 >> 11, t0 = row0 & 2047;
        if (p == 2) {
          u32x2 pv;
          pv.x = pack2(acc[i][j][0] + bb, acc[i][j][1] + bb);
          pv.y = pack2(acc[i][j][2] + bb, acc[i][j][3] + bb);
          *(u32x2*)&VTb[((size_t)(b_ * 16 + h) * 64 + d) * 2048 + t0] = pv;
        } else {
          u16* dst = (p == 0 ? Qb : Kb);
#pragma unroll
          for (int r = 0; r < 4; r++)
            dst[((size_t)(b_ * 16 + h) * 2048 + (t0 + r)) * 64 + d] = f2bf(acc[i][j][r] + bb);
        }
      }
    }
  } else {
#pragma unroll
    for (int j = 0; j < 4; j++) {
      int col = ccol + j * 16 + lr;
      float bb = bias[col];
#pragma unroll
      for (int i = 0; i < 4; i++) {
        int row0 = crow + i * 16 + lg * 4;
#pragma unroll
        for (int r = 0; r < 4; r++)
          outF[(size_t)(row0 + r) * 1024 + col] = acc[i][j][r] + bb;
      }
    }
  }
}

// ---------------------------------------------------------------- flash attention (causal, 32x32)
// Column-split pairing: each wave's 32 MFMA q-columns = 16 rows of short tile t + 16 rows of
// long tile (31-t) (64-row tiles). m/l/o are per-lane, so one register context serves both;
// the short tile's kv-range rides free inside the long tile's MFMAs (masked lanes: p=0).
// Uniform per-block work = 32-t kv tiles. K/V double-buffered in LDS, XOR-swizzled both sides.
DEV void stage_kv(const u16* __restrict__ Kh, const u16* __restrict__ Vh, int kv0,
                  u16* Ksb, u16* Vsb, int tid) {
#pragma unroll
  for (int j = 0; j < 2; j++) {
    int ci = j * 256 + tid;                 // 512 chunks of 16B = 64 rows x 8 slots
    int row = ci >> 3, slot = ci & 7;
    int ss = slot ^ (row & 7);
    __builtin_amdgcn_global_load_lds(
        (const __attribute__((address_space(1))) void*)(Kh + (size_t)(kv0 + row) * 64 + ss * 8),
        (__attribute__((address_space(3))) void*)(Ksb + ci * 8), 16, 0, 0);
    __builtin_amdgcn_global_load_lds(
        (const __attribute__((address_space(1))) void*)(Vh + (size_t)row * 2048 + kv0 + ss * 8),
        (__attribute__((address_space(3))) void*)(Vsb + ci * 8), 16, 0, 0);
  }
}

__global__ __launch_bounds__(256, 4) void attn_kernel(
    const u16* __restrict__ Qb, const u16* __restrict__ Kb, const u16* __restrict__ VTb,
    u16* __restrict__ cat) {
  __shared__ u16 Ks[2][64 * 64];
  __shared__ u16 Vs[2][64 * 64];
  int bid = blockIdx.x;                 // 1024 = 16 t-pairs x 64 bh
  int t = bid >> 6;                     // 0..15 : tiles (t, 31-t), 64 rows each
  int bh = bid & 63;
  int b = bh >> 4, h = bh & 15;
  int tid = threadIdx.x, wave = tid >> 6, lane = tid & 63;
  int l31 = lane & 31, hi = lane >> 5;
  int qrow = (l31 < 16) ? (t * 64 + wave * 16 + l31)
                        : ((31 - t) * 64 + wave * 16 + (l31 - 16));

  const u16* Qh = Qb + (size_t)bh * 2048 * 64;
  const u16* Kh = Kb + (size_t)bh * 2048 * 64;
  const u16* Vh = VTb + (size_t)bh * 64 * 2048;

  bf16x8 qf[4];                         // B-operand: col=q (lane&31), k = ks*16 + hi*8 + i
#pragma unroll
  for (int ks = 0; ks < 4; ks++)
    qf[ks] = *(const bf16x8*)&Qh[(size_t)qrow * 64 + ks * 16 + hi * 8];

  f32x16 o0 = zero16(), o1 = zero16();
  float m_run = -1e30f, l_run = 0.f;
  int iters = 32 - t;

  stage_kv(Kh, Vh, 0, Ks[0], Vs[0], tid);
  __syncthreads();
  int cur = 0;

  for (int kvt = 0; kvt < iters; ++kvt) {
    int kv0 = kvt * 64;
    if (kvt + 1 < iters) stage_kv(Kh, Vh, kv0 + 64, Ks[cur ^ 1], Vs[cur ^ 1], tid);

    // ---- QK^T : S^T[kv][q]
    f32x16 s0 = zero16(), s1 = zero16();
    __builtin_amdgcn_s_setprio(1);
#pragma unroll
    for (int ks = 0; ks < 4; ks++) {
      int r0 = l31, r1 = 32 + l31;
      bf16x8 k0 = *(const bf16x8*)&Ks[cur][r0 * 64 + (((ks * 2 + hi) ^ (r0 & 7)) * 8)];
      bf16x8 k1 = *(const bf16x8*)&Ks[cur][r1 * 64 + (((ks * 2 + hi) ^ (r1 & 7)) * 8)];
      s0 = __builtin_amdgcn_mfma_f32_32x32x16_bf16(k0, qf[ks], s0, 0, 0, 0);
      s1 = __builtin_amdgcn_mfma_f32_32x32x16_bf16(k1, qf[ks], s1, 0, 0, 0);
    }
    __builtin_amdgcn_s_setprio(0);

    // ---- causal mask (per-lane row = qrow; element kv = kv0 + blk*32 + (r&3)+8*(r>>2)+4*hi)
    if (__any(kv0 + 63 > qrow)) {
      int relh = qrow - kv0 - 4 * hi;
#pragma unroll
      for (int r = 0; r < 16; r++) {
        int off = (r & 3) + 8 * (r >> 2);
        s0[r] = (off > relh) ? -1e30f : s0[r];
        s1[r] = (off + 32 > relh) ? -1e30f : s1[r];
      }
    }

    // ---- online softmax (exp2 domain), defer-max rescale (T13)
    float tm0 = fmaxf(s0[0], s1[0]), tm1 = fmaxf(s0[1], s1[1]);
    float tm2 = fmaxf(s0[2], s1[2]), tm3 = fmaxf(s0[3], s1[3]);
#pragma unroll
    for (int j = 1; j < 4; j++) {
      tm0 = fmaxf(tm0, fmaxf(s0[j * 4 + 0], s1[j * 4 + 0]));
      tm1 = fmaxf(tm1, fmaxf(s0[j * 4 + 1], s1[j * 4 + 1]));
      tm2 = fmaxf(tm2, fmaxf(s0[j * 4 + 2], s1[j * 4 + 2]));
      tm3 = fmaxf(tm3, fmaxf(s0[j * 4 + 3], s1[j * 4 + 3]));
    }
    float tmax = fmaxf(fmaxf(tm0, tm1), fmaxf(tm2, tm3));
    tmax = fmaxf(tmax, __shfl_xor(tmax, 32));
    float corr = 1.f;
    if (!__all(tmax <= m_run + 8.f)) {
      float m_new = fmaxf(m_run, tmax);
      corr = exp2_hw(m_run - m_new);
      o0 = o0 * corr;
      o1 = o1 * corr;
      m_run = m_new;
    }
    float t0 = 0.f, t1 = 0.f, t2 = 0.f, t3 = 0.f;
#pragma unroll
    for (int j = 0; j < 4; j++) {
      float p00 = exp2_hw(s0[j * 4 + 0] - m_run); s0[j * 4 + 0] = p00; t0 += p00;
      float p01 = exp2_hw(s0[j * 4 + 1] - m_run); s0[j * 4 + 1] = p01; t1 += p01;
      float p02 = exp2_hw(s0[j * 4 + 2] - m_run); s0[j * 4 + 2] = p02; t2 += p02;
      float p03 = exp2_hw(s0[j * 4 + 3] - m_run); s0[j * 4 + 3] = p03; t3 += p03;
      float p10 = exp2_hw(s1[j * 4 + 0] - m_run); s1[j * 4 + 0] = p10; t0 += p10;
      float p11 = exp2_hw(s1[j * 4 + 1] - m_run); s1[j * 4 + 1] = p11; t1 += p11;
      float p12 = exp2_hw(s1[j * 4 + 2] - m_run); s1[j * 4 + 2] = p12; t2 += p12;
      float p13 = exp2_hw(s1[j * 4 + 3] - m_run); s1[j * 4 + 3] = p13; t3 += p13;
    }
    float ts = (t0 + t1) + (t2 + t3);
    ts += __shfl_xor(ts, 32);
    l_run = l_run * corr + ts;

    // ---- PV : O^T[d][q]; P-fragments built just-in-time (T12), s dies progressively
    __builtin_amdgcn_s_setprio(1);
#pragma unroll
    for (int ks = 0; ks < 4; ks++) {
      const f32x16& sb = (ks < 2) ? s0 : s1;
      int g2 = (ks & 1) * 8;                 // element base 2*g
      u32 a  = cvtpk_bf16(sb[g2 + 0], sb[g2 + 1]);   // pk[g+0]
      u32 c  = cvtpk_bf16(sb[g2 + 2], sb[g2 + 3]);   // pk[g+1]
      u32 bb = cvtpk_bf16(sb[g2 + 4], sb[g2 + 5]);   // pk[g+2]
      u32 d  = cvtpk_bf16(sb[g2 + 6], sb[g2 + 7]);   // pk[g+3]
      pl32swap(a, bb);
      pl32swap(c, d);
      u32x4 wv; wv.x = a; wv.y = c; wv.z = bb; wv.w = d;
      bf16x8 pf = __builtin_bit_cast(bf16x8, wv);
      int r0 = l31, r1 = 32 + l31;
      bf16x8 v0 = *(const bf16x8*)&Vs[cur][r0 * 64 + (((ks * 2 + hi) ^ (r0 & 7)) * 8)];
      bf16x8 v1 = *(const bf16x8*)&Vs[cur][r1 * 64 + (((ks * 2 + hi) ^ (r1 & 7)) * 8)];
      o0 = __builtin_amdgcn_mfma_f32_32x32x16_bf16(v0, pf, o0, 0, 0, 0);
      o1 = __builtin_amdgcn_mfma_f32_32x32x16_bf16(v1, pf, o1, 0, 0, 0);
    }
    __builtin_amdgcn_s_setprio(0);

    __syncthreads();
    cur ^= 1;
  }

  float li = 1.0f / l_run;
#pragma unroll
  for (int m = 0; m < 8; m++) {
    int dbase = 2 * (m & 1) + 8 * (m >> 1) + 4 * hi;
    u32 w0 = cvtpk_bf16(o0[2 * m] * li, o0[2 * m + 1] * li);
    u32 w1 = cvtpk_bf16(o1[2 * m] * li, o1[2 * m + 1] * li);
    *(u32*)&cat[(size_t)(b * 2048 + qrow) * 1024 + h * 64 + dbase] = w0;
    *(u32*)&cat[(size_t)(b * 2048 + qrow) * 1024 + h * 64 + 32 + dbase] = w1;
  }
}

// ---------------------------------------------------------------- launch
extern "C" void kernel_launch(void* const* d_in, const int* in_sizes, int n_in,
                              void* d_out, int out_size, void* d_ws, size_t ws_size,
                              hipStream_t stream) {
  const float* x  = (const float*)d_in[0];
  const float* Wq = (const float*)d_in[1];
  const float* bq = (const float*)d_in[2];
  const float* Wk = (const float*)d_in[3];
  const float* bk = (const float*)d_in[4];
  const float* Wv = (const float*)d_in[5];
  const float* bv = (const float*)d_in[6];
  const float* Wp = (const float*)d_in[7];
  const float* bp = (const float*)d_in[8];

  char* w = (char*)d_ws;
  u16* xbf    = (u16*)w;                 w += (size_t)8192 * 1024 * 2;
  u16* wqkvT  = (u16*)w;                 w += (size_t)3072 * 1024 * 2;
  u16* wpT    = (u16*)w;                 w += (size_t)1024 * 1024 * 2;
  float* bqkv = (float*)w;               w += (size_t)3072 * 4;
  u16* Qb     = (u16*)w;                 w += (size_t)64 * 2048 * 64 * 2;
  u16* Kb     = (u16*)w;                 w += (size_t)64 * 2048 * 64 * 2;
  u16* VTb    = (u16*)w;                 w += (size_t)64 * 64 * 2048 * 2;
  u16* cat    = (u16*)w;                 w += (size_t)8192 * 1024 * 2;

  prep_x_kernel<<<4096, 256, 0, stream>>>(x, bq, bk, bv, xbf, bqkv);
  prep_w_kernel<<<1024, 256, 0, stream>>>(Wq, Wk, Wv, Wp, wqkvT, wpT);
  gemm128_kernel<<<1536, 256, 0, stream>>>(xbf, wqkvT, bqkv, 24, 0, Qb, Kb, VTb, nullptr);
  attn_kernel<<<1024, 256, 0, stream>>>(Qb, Kb, VTb, cat);
  gemm128_kernel<<<512, 256, 0, stream>>>(cat, wpT, bp, 8, 1, nullptr, nullptr, nullptr, (float*)d_out);
}

// Round 5
// 167.408 us; speedup vs baseline: 1.4106x; 1.0860x over previous
//
#include <hip/hip_runtime.h>

// MHA fused forward for B=4,T=2048,E=1024,H=16,D=64 on gfx950.
// prep (bf16 cast + weight transpose, QK-scale folded into Wq) -> GEMM1 (QKV) -> flash attn
// (32x32 MFMA, per-tile blocks longest-first, T12 cvt_pk+permlane32_swap) -> GEMM2 (out proj).

typedef __attribute__((ext_vector_type(8))) __bf16 bf16x8;
typedef __attribute__((ext_vector_type(4))) float f32x4;
typedef __attribute__((ext_vector_type(16))) float f32x16;
typedef __attribute__((ext_vector_type(4))) unsigned int u32x4;
typedef __attribute__((ext_vector_type(2))) unsigned int u32x2;
typedef unsigned short u16;
typedef unsigned int u32;

#define DEV __device__ __forceinline__

#define QK_SCALE 0.18033688011112042f   // 0.125 * log2(e) : folded into Wq/bq

DEV u16 f2bf(float f) {          // round-to-nearest-even f32 -> bf16 (inputs never NaN)
  u32 u = __builtin_bit_cast(u32, f);
  u += 0x7fffu + ((u >> 16) & 1u);
  return (u16)(u >> 16);
}
DEV u32 pack2(float a, float b) { return (u32)f2bf(a) | ((u32)f2bf(b) << 16); }

DEV float exp2_hw(float x) { float r; asm("v_exp_f32 %0, %1" : "=v"(r) : "v"(x)); return r; }
DEV u32 cvtpk_bf16(float lo, float hi) {
  u32 r; asm("v_cvt_pk_bf16_f32 %0, %1, %2" : "=v"(r) : "v"(lo), "v"(hi)); return r;
}
DEV void pl32swap(u32& a, u32& b) { asm("v_permlane32_swap_b32 %0, %1" : "+v"(a), "+v"(b)); }
DEV float max3f(float a, float b, float c) {
  float r; asm("v_max3_f32 %0, %1, %2, %3" : "=v"(r) : "v"(a), "v"(b), "v"(c)); return r;
}

DEV f32x16 zero16() { f32x16 z;
#pragma unroll
  for (int i = 0; i < 16; i++) z[i] = 0.f;
  return z; }

// ---------------------------------------------------------------- prep: x->bf16, bias concat
__global__ __launch_bounds__(256) void prep_x_kernel(
    const float* __restrict__ x, const float* __restrict__ bq, const float* __restrict__ bk,
    const float* __restrict__ bv, u16* __restrict__ xbf, float* __restrict__ bqkv) {
  int gid = blockIdx.x * 256 + threadIdx.x;
  if (gid < 3072) {
    float v = (gid < 1024) ? bq[gid] * QK_SCALE : (gid < 2048 ? bk[gid - 1024] : bv[gid - 2048]);
    bqkv[gid] = v;
  }
  const float4* xv = (const float4*)x;
  float4 f0 = xv[(size_t)gid * 2];
  float4 f1 = xv[(size_t)gid * 2 + 1];
  u32x4 st;
  st.x = pack2(f0.x, f0.y); st.y = pack2(f0.z, f0.w);
  st.z = pack2(f1.x, f1.y); st.w = pack2(f1.z, f1.w);
  *(u32x4*)&xbf[(size_t)gid * 8] = st;
}

// ---------------------------------------------------------------- prep: weight transposes to B^T bf16
__global__ __launch_bounds__(256) void prep_w_kernel(
    const float* __restrict__ Wq, const float* __restrict__ Wk, const float* __restrict__ Wv,
    const float* __restrict__ Wp, u16* __restrict__ wqkvT, u16* __restrict__ wpT) {
  __shared__ float t[64][65];
  int bid = blockIdx.x, tid = threadIdx.x;
  int r0 = tid >> 6, c = tid & 63;
  if (bid < 768) {
    int p = bid >> 8, rem = bid & 255, h = rem >> 4, et = rem & 15;
    float sc = (p == 0) ? QK_SCALE : 1.0f;
    const float* src = (p == 0 ? Wq : (p == 1 ? Wk : Wv)) + ((size_t)h * 1024 + et * 64) * 64;
#pragma unroll
    for (int i = 0; i < 16; i++) { int e = r0 + i * 4; t[e][c] = src[(size_t)e * 64 + c]; }
    __syncthreads();
    u16* dst = wqkvT + ((size_t)p * 1024 + h * 64) * 1024 + et * 64;
#pragma unroll
    for (int i = 0; i < 16; i++) { int d = r0 + i * 4; dst[(size_t)d * 1024 + c] = f2bf(t[c][d] * sc); }
  } else {
    int b2 = bid - 768, rt = b2 >> 4, ct = b2 & 15;
#pragma unroll
    for (int i = 0; i < 16; i++) { int e = r0 + i * 4; t[e][c] = Wp[(size_t)(rt * 64 + e) * 1024 + ct * 64 + c]; }
    __syncthreads();
#pragma unroll
    for (int i = 0; i < 16; i++) { int f = r0 + i * 4; wpT[(size_t)(ct * 64 + f) * 1024 + rt * 64 + c] = f2bf(t[c][f]); }
  }
}

// ---------------------------------------------------------------- GEMM 128x128 tile, K=1024, BK=64
DEV void stage_tile(const u16* __restrict__ X, int row0, int k0, u16* lds, int tid) {
#pragma unroll
  for (int j = 0; j < 4; j++) {
    int ci = j * 256 + tid;
    int row = ci >> 3, slot = ci & 7;
    int srcslot = slot ^ (row & 7);
    const u16* gp = X + (size_t)(row0 + row) * 1024 + k0 + srcslot * 8;
    __builtin_amdgcn_global_load_lds((const __attribute__((address_space(1))) void*)gp,
                                     (__attribute__((address_space(3))) void*)(lds + ci * 8),
                                     16, 0, 0);
  }
}

__global__ __launch_bounds__(256) void gemm128_kernel(
    const u16* __restrict__ A, const u16* __restrict__ Bt, const float* __restrict__ bias,
    int tilesN, int mode, u16* __restrict__ Qb, u16* __restrict__ Kb, u16* __restrict__ VTb,
    float* __restrict__ outF) {
  __shared__ u16 As[128 * 64];
  __shared__ u16 Bs[128 * 64];
  int nwg = gridDim.x;
  int bid = blockIdx.x;
  int swz = (bid % 8) * (nwg / 8) + bid / 8;
  int bm = swz / tilesN, bn = swz % tilesN;
  int tid = threadIdx.x;
  int lane = tid & 63, wave = tid >> 6;
  int wm = wave >> 1, wn = wave & 1;
  int lr = lane & 15, lg = lane >> 4;

  f32x4 acc[4][4];
#pragma unroll
  for (int i = 0; i < 4; i++)
#pragma unroll
    for (int j = 0; j < 4; j++) acc[i][j] = f32x4{0.f, 0.f, 0.f, 0.f};

  for (int k0 = 0; k0 < 1024; k0 += 64) {
    stage_tile(A, bm * 128, k0, As, tid);
    stage_tile(Bt, bn * 128, k0, Bs, tid);
    __syncthreads();
#pragma unroll
    for (int kf = 0; kf < 2; kf++) {
      bf16x8 af[4], bfr[4];
#pragma unroll
      for (int i = 0; i < 4; i++) {
        int ra = wm * 64 + i * 16 + lr;
        af[i] = *(const bf16x8*)&As[ra * 64 + (((lg + kf * 4) ^ (ra & 7)) * 8)];
        int rb = wn * 64 + i * 16 + lr;
        bfr[i] = *(const bf16x8*)&Bs[rb * 64 + (((lg + kf * 4) ^ (rb & 7)) * 8)];
      }
      __builtin_amdgcn_s_setprio(1);
#pragma unroll
      for (int i = 0; i < 4; i++)
#pragma unroll
        for (int j = 0; j < 4; j++)
          acc[i][j] = __builtin_amdgcn_mfma_f32_16x16x32_bf16(af[i], bfr[j], acc[i][j], 0, 0, 0);
      __builtin_amdgcn_s_setprio(0);
    }
    __syncthreads();
  }

  int crow = bm * 128 + wm * 64;
  int ccol = bn * 128 + wn * 64;
  if (mode == 0) {
#pragma unroll
    for (int j = 0; j < 4; j++) {
      int col = ccol + j * 16 + lr;
      float bb = bias[col];
      int p = col >> 10, h = (col >> 6) & 15, d = col & 63;
#pragma unroll
      for (int i = 0; i < 4; i++) {
        int row0 = crow + i * 16 + lg * 4;
        int b_ = row0 >> 11, t0 = row0 & 2047;
        if (p == 2) {
          u32x2 pv;
          pv.x = pack2(acc[i][j][0] + bb, acc[i][j][1] + bb);
          pv.y = pack2(acc[i][j][2] + bb, acc[i][j][3] + bb);
          *(u32x2*)&VTb[((size_t)(b_ * 16 + h) * 64 + d) * 2048 + t0] = pv;
        } else {
          u16* dst = (p == 0 ? Qb : Kb);
#pragma unroll
          for (int r = 0; r < 4; r++)
            dst[((size_t)(b_ * 16 + h) * 2048 + (t0 + r)) * 64 + d] = f2bf(acc[i][j][r] + bb);
        }
      }
    }
  } else {
#pragma unroll
    for (int j = 0; j < 4; j++) {
      int col = ccol + j * 16 + lr;
      float bb = bias[col];
#pragma unroll
      for (int i = 0; i < 4; i++) {
        int row0 = crow + i * 16 + lg * 4;
#pragma unroll
        for (int r = 0; r < 4; r++)
          outF[(size_t)(row0 + r) * 1024 + col] = acc[i][j][r] + bb;
      }
    }
  }
}

// ---------------------------------------------------------------- flash attention (causal, 32x32)
// 2048 blocks of 2 waves; block = one 64-row q-tile t (t=0..31) of one (b,h); iters = t+1.
// Longest-first dispatch (t = 31-(bid>>6)) + oversubscription (LDS caps ~5 blocks/CU, 2048
// blocks queued) gives dynamic load balance with zero column waste. Causal mask only on the
// diagonal iteration. K/V double-buffered in LDS, XOR-swizzled both sides (rule #21).
DEV void stage_kv128(const u16* __restrict__ Kh, const u16* __restrict__ Vh, int kv0,
                     u16* Ksb, u16* Vsb, int tid) {
#pragma unroll
  for (int j = 0; j < 4; j++) {
    int ci = j * 128 + tid;                 // 512 chunks of 16B = 64 rows x 8 slots
    int row = ci >> 3, slot = ci & 7;
    int ss = slot ^ (row & 7);
    __builtin_amdgcn_global_load_lds(
        (const __attribute__((address_space(1))) void*)(Kh + (size_t)(kv0 + row) * 64 + ss * 8),
        (__attribute__((address_space(3))) void*)(Ksb + ci * 8), 16, 0, 0);
    __builtin_amdgcn_global_load_lds(
        (const __attribute__((address_space(1))) void*)(Vh + (size_t)row * 2048 + kv0 + ss * 8),
        (__attribute__((address_space(3))) void*)(Vsb + ci * 8), 16, 0, 0);
  }
}

__global__ __launch_bounds__(128, 2) void attn_kernel(
    const u16* __restrict__ Qb, const u16* __restrict__ Kb, const u16* __restrict__ VTb,
    u16* __restrict__ cat) {
  __shared__ u16 Ks[2][64 * 64];
  __shared__ u16 Vs[2][64 * 64];
  int bid = blockIdx.x;                 // 2048 = 32 t x 64 bh, longest-first
  int t = 31 - (bid >> 6);              // q-tile index: rows [64t, 64t+64)
  int bh = bid & 63;
  int b = bh >> 4, h = bh & 15;
  int tid = threadIdx.x, wave = tid >> 6, lane = tid & 63;
  int l31 = lane & 31, hi = lane >> 5;
  int qrow = t * 64 + wave * 32 + l31;

  const u16* Qh = Qb + (size_t)bh * 2048 * 64;
  const u16* Kh = Kb + (size_t)bh * 2048 * 64;
  const u16* Vh = VTb + (size_t)bh * 64 * 2048;

  bf16x8 qf[4];                         // B-operand: col=q (lane&31), k = ks*16 + hi*8 + i
#pragma unroll
  for (int ks = 0; ks < 4; ks++)
    qf[ks] = *(const bf16x8*)&Qh[(size_t)qrow * 64 + ks * 16 + hi * 8];

  // precomputed swizzled LDS byte offsets (row l31; row+32 differs by +4096B, same XOR)
  u32 loff[4];
#pragma unroll
  for (int ks = 0; ks < 4; ks++)
    loff[ks] = (u32)(l31 * 128 + (((ks * 2 + hi) ^ (l31 & 7)) * 16));

  f32x16 o0 = zero16(), o1 = zero16();
  float m_run = -1e30f, l_run = 0.f;
  int iters = t + 1;

  stage_kv128(Kh, Vh, 0, Ks[0], Vs[0], tid);
  __syncthreads();
  int cur = 0;

  for (int kvt = 0; kvt < iters; ++kvt) {
    int kv0 = kvt * 64;
    if (kvt + 1 < iters) stage_kv128(Kh, Vh, kv0 + 64, Ks[cur ^ 1], Vs[cur ^ 1], tid);

    // ---- QK^T : S^T[kv][q]
    f32x16 s0 = zero16(), s1 = zero16();
    const char* kb = (const char*)&Ks[cur][0];
    __builtin_amdgcn_s_setprio(1);
#pragma unroll
    for (int ks = 0; ks < 4; ks++) {
      bf16x8 k0 = *(const bf16x8*)(kb + loff[ks]);
      bf16x8 k1 = *(const bf16x8*)(kb + loff[ks] + 4096);
      s0 = __builtin_amdgcn_mfma_f32_32x32x16_bf16(k0, qf[ks], s0, 0, 0, 0);
      s1 = __builtin_amdgcn_mfma_f32_32x32x16_bf16(k1, qf[ks], s1, 0, 0, 0);
    }
    __builtin_amdgcn_s_setprio(0);

    // ---- causal mask: only the diagonal tile (kvt == t)
    if (kvt == t) {
      int relh = qrow - kv0 - 4 * hi;
#pragma unroll
      for (int r = 0; r < 16; r++) {
        int off = (r & 3) + 8 * (r >> 2);
        s0[r] = (off > relh) ? -1e30f : s0[r];
        s1[r] = (off + 32 > relh) ? -1e30f : s1[r];
      }
    }

    // ---- online softmax (exp2 domain), defer-max rescale (T13), max3 tree
    float ta = max3f(s0[0], s0[1], s0[2]);
    float tb = max3f(s0[4], s0[5], s0[6]);
    float tc = max3f(s0[8], s0[9], s0[10]);
    float td = max3f(s0[12], s0[13], s0[14]);
    ta = max3f(ta, s0[3], s1[0]);
    tb = max3f(tb, s0[7], s1[4]);
    tc = max3f(tc, s0[11], s1[8]);
    td = max3f(td, s0[15], s1[12]);
    ta = max3f(ta, s1[1], s1[2]);
    tb = max3f(tb, s1[5], s1[6]);
    tc = max3f(tc, s1[9], s1[10]);
    td = max3f(td, s1[13], s1[14]);
    ta = max3f(ta, s1[3], tb);
    tc = max3f(tc, s1[7], td);
    float tmax = max3f(ta, tc, s1[11]);
    tmax = fmaxf(tmax, s1[15]);
    tmax = fmaxf(tmax, __shfl_xor(tmax, 32));
    float corr = 1.f;
    if (!__all(tmax <= m_run + 8.f)) {
      float m_new = fmaxf(m_run, tmax);
      corr = exp2_hw(m_run - m_new);
      o0 = o0 * corr;
      o1 = o1 * corr;
      m_run = m_new;
    }
    float t0 = 0.f, t1 = 0.f, t2 = 0.f, t3 = 0.f;
#pragma unroll
    for (int j = 0; j < 4; j++) {
      float p00 = exp2_hw(s0[j * 4 + 0] - m_run); s0[j * 4 + 0] = p00; t0 += p00;
      float p01 = exp2_hw(s0[j * 4 + 1] - m_run); s0[j * 4 + 1] = p01; t1 += p01;
      float p02 = exp2_hw(s0[j * 4 + 2] - m_run); s0[j * 4 + 2] = p02; t2 += p02;
      float p03 = exp2_hw(s0[j * 4 + 3] - m_run); s0[j * 4 + 3] = p03; t3 += p03;
      float p10 = exp2_hw(s1[j * 4 + 0] - m_run); s1[j * 4 + 0] = p10; t0 += p10;
      float p11 = exp2_hw(s1[j * 4 + 1] - m_run); s1[j * 4 + 1] = p11; t1 += p11;
      float p12 = exp2_hw(s1[j * 4 + 2] - m_run); s1[j * 4 + 2] = p12; t2 += p12;
      float p13 = exp2_hw(s1[j * 4 + 3] - m_run); s1[j * 4 + 3] = p13; t3 += p13;
    }
    float ts = (t0 + t1) + (t2 + t3);
    ts += __shfl_xor(ts, 32);
    l_run = l_run * corr + ts;

    // ---- PV : O^T[d][q]; P-fragments built just-in-time (T12), s dies progressively
    const char* vb = (const char*)&Vs[cur][0];
    __builtin_amdgcn_s_setprio(1);
#pragma unroll
    for (int ks = 0; ks < 4; ks++) {
      const f32x16& sb = (ks < 2) ? s0 : s1;
      int g2 = (ks & 1) * 8;
      u32 a  = cvtpk_bf16(sb[g2 + 0], sb[g2 + 1]);
      u32 c  = cvtpk_bf16(sb[g2 + 2], sb[g2 + 3]);
      u32 bb = cvtpk_bf16(sb[g2 + 4], sb[g2 + 5]);
      u32 d  = cvtpk_bf16(sb[g2 + 6], sb[g2 + 7]);
      pl32swap(a, bb);
      pl32swap(c, d);
      u32x4 wv; wv.x = a; wv.y = c; wv.z = bb; wv.w = d;
      bf16x8 pf = __builtin_bit_cast(bf16x8, wv);
      bf16x8 v0 = *(const bf16x8*)(vb + loff[ks]);
      bf16x8 v1 = *(const bf16x8*)(vb + loff[ks] + 4096);
      o0 = __builtin_amdgcn_mfma_f32_32x32x16_bf16(v0, pf, o0, 0, 0, 0);
      o1 = __builtin_amdgcn_mfma_f32_32x32x16_bf16(v1, pf, o1, 0, 0, 0);
    }
    __builtin_amdgcn_s_setprio(0);

    __syncthreads();
    cur ^= 1;
  }

  float li = 1.0f / l_run;
#pragma unroll
  for (int m = 0; m < 8; m++) {
    int dbase = 2 * (m & 1) + 8 * (m >> 1) + 4 * hi;
    u32 w0 = cvtpk_bf16(o0[2 * m] * li, o0[2 * m + 1] * li);
    u32 w1 = cvtpk_bf16(o1[2 * m] * li, o1[2 * m + 1] * li);
    *(u32*)&cat[(size_t)(b * 2048 + qrow) * 1024 + h * 64 + dbase] = w0;
    *(u32*)&cat[(size_t)(b * 2048 + qrow) * 1024 + h * 64 + 32 + dbase] = w1;
  }
}

// ---------------------------------------------------------------- launch
extern "C" void kernel_launch(void* const* d_in, const int* in_sizes, int n_in,
                              void* d_out, int out_size, void* d_ws, size_t ws_size,
                              hipStream_t stream) {
  const float* x  = (const float*)d_in[0];
  const float* Wq = (const float*)d_in[1];
  const float* bq = (const float*)d_in[2];
  const float* Wk = (const float*)d_in[3];
  const float* bk = (const float*)d_in[4];
  const float* Wv = (const float*)d_in[5];
  const float* bv = (const float*)d_in[6];
  const float* Wp = (const float*)d_in[7];
  const float* bp = (const float*)d_in[8];

  char* w = (char*)d_ws;
  u16* xbf    = (u16*)w;                 w += (size_t)8192 * 1024 * 2;
  u16* wqkvT  = (u16*)w;                 w += (size_t)3072 * 1024 * 2;
  u16* wpT    = (u16*)w;                 w += (size_t)1024 * 1024 * 2;
  float* bqkv = (float*)w;               w += (size_t)3072 * 4;
  u16* Qb     = (u16*)w;                 w += (size_t)64 * 2048 * 64 * 2;
  u16* Kb     = (u16*)w;                 w += (size_t)64 * 2048 * 64 * 2;
  u16* VTb    = (u16*)w;                 w += (size_t)64 * 64 * 2048 * 2;
  u16* cat    = (u16*)w;                 w += (size_t)8192 * 1024 * 2;

  prep_x_kernel<<<4096, 256, 0, stream>>>(x, bq, bk, bv, xbf, bqkv);
  prep_w_kernel<<<1024, 256, 0, stream>>>(Wq, Wk, Wv, Wp, wqkvT, wpT);
  gemm128_kernel<<<1536, 256, 0, stream>>>(xbf, wqkvT, bqkv, 24, 0, Qb, Kb, VTb, nullptr);
  attn_kernel<<<2048, 128, 0, stream>>>(Qb, Kb, VTb, cat);
  gemm128_kernel<<<512, 256, 0, stream>>>(cat, wpT, bp, 8, 1, nullptr, nullptr, nullptr, (float*)d_out);
}

// Round 6
// 166.012 us; speedup vs baseline: 1.4225x; 1.0084x over previous
//
#include <hip/hip_runtime.h>

// MHA fused forward for B=4,T=2048,E=1024,H=16,D=64 on gfx950.
// prep (bf16 cast + weight transpose, QK-scale folded into Wq) -> GEMM1 (QKV, 8-phase 256x128)
// -> flash attn (32x32 MFMA, longest-first blocks, T12) -> GEMM2 (out proj, 8-phase 256x128).

typedef __attribute__((ext_vector_type(8))) __bf16 bf16x8;
typedef __attribute__((ext_vector_type(4))) float f32x4;
typedef __attribute__((ext_vector_type(16))) float f32x16;
typedef __attribute__((ext_vector_type(4))) unsigned int u32x4;
typedef __attribute__((ext_vector_type(2))) unsigned int u32x2;
typedef unsigned short u16;
typedef unsigned int u32;

#define DEV __device__ __forceinline__

#define QK_SCALE 0.18033688011112042f   // 0.125 * log2(e) : folded into Wq/bq

DEV u16 f2bf(float f) {          // round-to-nearest-even f32 -> bf16 (inputs never NaN)
  u32 u = __builtin_bit_cast(u32, f);
  u += 0x7fffu + ((u >> 16) & 1u);
  return (u16)(u >> 16);
}
DEV u32 pack2(float a, float b) { return (u32)f2bf(a) | ((u32)f2bf(b) << 16); }

DEV float exp2_hw(float x) { float r; asm("v_exp_f32 %0, %1" : "=v"(r) : "v"(x)); return r; }
DEV u32 cvtpk_bf16(float lo, float hi) {
  u32 r; asm("v_cvt_pk_bf16_f32 %0, %1, %2" : "=v"(r) : "v"(lo), "v"(hi)); return r;
}
DEV void pl32swap(u32& a, u32& b) { asm("v_permlane32_swap_b32 %0, %1" : "+v"(a), "+v"(b)); }
DEV float max3f(float a, float b, float c) {
  float r; asm("v_max3_f32 %0, %1, %2, %3" : "=v"(r) : "v"(a), "v"(b), "v"(c)); return r;
}

DEV f32x16 zero16() { f32x16 z;
#pragma unroll
  for (int i = 0; i < 16; i++) z[i] = 0.f;
  return z; }

DEV void gll16(const u16* g, u16* l) {
  __builtin_amdgcn_global_load_lds((const __attribute__((address_space(1))) void*)g,
                                   (__attribute__((address_space(3))) void*)l, 16, 0, 0);
}

#define SCHEDB() __builtin_amdgcn_sched_barrier(0)
#define SBAR()   do { __builtin_amdgcn_s_barrier(); SCHEDB(); } while (0)
#define LGKM0()  do { asm volatile("s_waitcnt lgkmcnt(0)" ::: "memory"); SCHEDB(); } while (0)

// ---------------------------------------------------------------- prep: x->bf16, bias concat
__global__ __launch_bounds__(256) void prep_x_kernel(
    const float* __restrict__ x, const float* __restrict__ bq, const float* __restrict__ bk,
    const float* __restrict__ bv, u16* __restrict__ xbf, float* __restrict__ bqkv) {
  int gid = blockIdx.x * 256 + threadIdx.x;
  if (gid < 3072) {
    float v = (gid < 1024) ? bq[gid] * QK_SCALE : (gid < 2048 ? bk[gid - 1024] : bv[gid - 2048]);
    bqkv[gid] = v;
  }
  const float4* xv = (const float4*)x;
  float4 f0 = xv[(size_t)gid * 2];
  float4 f1 = xv[(size_t)gid * 2 + 1];
  u32x4 st;
  st.x = pack2(f0.x, f0.y); st.y = pack2(f0.z, f0.w);
  st.z = pack2(f1.x, f1.y); st.w = pack2(f1.z, f1.w);
  *(u32x4*)&xbf[(size_t)gid * 8] = st;
}

// ---------------------------------------------------------------- prep: weight transposes to B^T bf16
__global__ __launch_bounds__(256) void prep_w_kernel(
    const float* __restrict__ Wq, const float* __restrict__ Wk, const float* __restrict__ Wv,
    const float* __restrict__ Wp, u16* __restrict__ wqkvT, u16* __restrict__ wpT) {
  __shared__ float t[64][65];
  int bid = blockIdx.x, tid = threadIdx.x;
  int r0 = tid >> 6, c = tid & 63;
  if (bid < 768) {
    int p = bid >> 8, rem = bid & 255, h = rem >> 4, et = rem & 15;
    float sc = (p == 0) ? QK_SCALE : 1.0f;
    const float* src = (p == 0 ? Wq : (p == 1 ? Wk : Wv)) + ((size_t)h * 1024 + et * 64) * 64;
#pragma unroll
    for (int i = 0; i < 16; i++) { int e = r0 + i * 4; t[e][c] = src[(size_t)e * 64 + c]; }
    __syncthreads();
    u16* dst = wqkvT + ((size_t)p * 1024 + h * 64) * 1024 + et * 64;
#pragma unroll
    for (int i = 0; i < 16; i++) { int d = r0 + i * 4; dst[(size_t)d * 1024 + c] = f2bf(t[c][d] * sc); }
  } else {
    int b2 = bid - 768, rt = b2 >> 4, ct = b2 & 15;
#pragma unroll
    for (int i = 0; i < 16; i++) { int e = r0 + i * 4; t[e][c] = Wp[(size_t)(rt * 64 + e) * 1024 + ct * 64 + c]; }
    __syncthreads();
#pragma unroll
    for (int i = 0; i < 16; i++) { int f = r0 + i * 4; wpT[(size_t)(ct * 64 + f) * 1024 + rt * 64 + c] = f2bf(t[c][f]); }
  }
}

// ---------------------------------------------------------------- GEMM 256x128 tile, 8-phase (T2+T3+T4+T5)
// BM=256, BN=128, BK=64, 512 thr (8 waves 4Mx2N, 64x64/wave). Triple-buffered K-tiles
// (prefetch distance 2) -> steady-state wait = vmcnt(6) once per K-tile, never 0.
// 4 phases/K-tile: {ds_read subtile || stage unit for t+2 -> s_barrier -> lgkmcnt(0) ->
// setprio(1) 8xMFMA setprio(0) -> s_barrier}. XOR swizzle slot^=(row&7) both sides.
#define SLOT_U16 24576            // A tile 256x64 (16384) + B tile 128x64 (8192)

DEV void stageA_unit(const u16* __restrict__ Asrc, int row0, int k0, int h, u16* An, int tid) {
#pragma unroll
  for (int jj = 0; jj < 2; jj++) {
    int idx = jj * 512 + tid;                 // 1024 chunks of 16B = 128 rows x 8 slots
    int row = h * 128 + (idx >> 3), slot = idx & 7;
    int ss = slot ^ (row & 7);
    gll16(Asrc + (size_t)(row0 + row) * 1024 + k0 + ss * 8, An + (size_t)row * 64 + slot * 8);
  }
}
DEV void stageB_unit(const u16* __restrict__ Bsrc, int row0, int k0, int h, u16* Bn, int tid) {
  int idx = tid;                              // 512 chunks = 64 rows x 8 slots
  int row = h * 64 + (idx >> 3), slot = idx & 7;
  int ss = slot ^ (row & 7);
  gll16(Bsrc + (size_t)(row0 + row) * 1024 + k0 + ss * 8, Bn + (size_t)row * 64 + slot * 8);
}

DEV bf16x8 ldsAB(const u16* base, int row, int kk, int lg) {
  return *(const bf16x8*)&base[row * 64 + (((lg + kk * 4) ^ (row & 7)) * 8)];
}

__global__ __launch_bounds__(512, 2) void gemm256_kernel(
    const u16* __restrict__ A, const u16* __restrict__ Bt, const float* __restrict__ bias,
    int tilesN, int mode, u16* __restrict__ Qb, u16* __restrict__ Kb, u16* __restrict__ VTb,
    float* __restrict__ outF) {
  __shared__ u16 lds[3 * SLOT_U16];           // 144 KiB
  int nwg = gridDim.x;
  int bid = blockIdx.x;
  int swz = (bid % 8) * (nwg / 8) + bid / 8;  // XCD-contiguous (nwg % 8 == 0)
  int bm = swz / tilesN, bn = swz % tilesN;
  int tid = threadIdx.x;
  int lane = tid & 63, wave = tid >> 6;
  int wm = wave >> 1, wn = wave & 1;          // 4M x 2N
  int lr = lane & 15, lg = lane >> 4;
  int aRow0 = bm * 256, bRow0 = bn * 128;
  int ar = wm * 64, br = wn * 64;             // wave's A-row / B-row (=N col) base in tile

  f32x4 acc[4][4];
#pragma unroll
  for (int i = 0; i < 4; i++)
#pragma unroll
    for (int j = 0; j < 4; j++) acc[i][j] = f32x4{0.f, 0.f, 0.f, 0.f};

  // prologue: stage tiles 0 and 1 (6 insts each)
#pragma unroll
  for (int pt = 0; pt < 2; pt++) {
    u16* As = lds + pt * SLOT_U16;
    stageA_unit(A, aRow0, pt * 64, 0, As, tid);
    stageA_unit(A, aRow0, pt * 64, 1, As, tid);
    stageB_unit(Bt, bRow0, pt * 64, 0, As + 16384, tid);
    stageB_unit(Bt, bRow0, pt * 64, 1, As + 16384, tid);
  }
  asm volatile("s_waitcnt vmcnt(6)" ::: "memory");   // tile0 landed; tile1 in flight
  SCHEDB();
  SBAR();

  int rs = 0;                                 // read slot = t % 3
  for (int t = 0; t < 16; ++t) {
    u16* Ac = lds + rs * SLOT_U16;
    u16* Bc = Ac + 16384;
    int ws = rs + 2; if (ws >= 3) ws -= 3;    // write slot = (t+2) % 3
    u16* An = lds + ws * SLOT_U16;
    u16* Bn = An + 16384;
    int k2 = (t + 2) * 64;
    bool st = (t + 2) < 16;

    // ---- P1: ds_read A(i=0,1) + B(j=0,1); stage A-unit0(t+2); MFMA acc[0..1][0..1]
    bf16x8 aLo[2][2], bLo[2][2];
#pragma unroll
    for (int i = 0; i < 2; i++)
#pragma unroll
      for (int kk = 0; kk < 2; kk++) aLo[i][kk] = ldsAB(Ac, ar + i * 16 + lr, kk, lg);
#pragma unroll
    for (int j = 0; j < 2; j++)
#pragma unroll
      for (int kk = 0; kk < 2; kk++) bLo[j][kk] = ldsAB(Bc, br + j * 16 + lr, kk, lg);
    if (st) stageA_unit(A, aRow0, k2, 0, An, tid);
    SBAR(); LGKM0();
    __builtin_amdgcn_s_setprio(1);
#pragma unroll
    for (int kk = 0; kk < 2; kk++)
#pragma unroll
      for (int i = 0; i < 2; i++)
#pragma unroll
        for (int j = 0; j < 2; j++)
          acc[i][j] = __builtin_amdgcn_mfma_f32_16x16x32_bf16(aLo[i][kk], bLo[j][kk], acc[i][j], 0, 0, 0);
    __builtin_amdgcn_s_setprio(0);
    SBAR();

    // ---- P2: ds_read B(j=2,3); stage B-unit0(t+2); MFMA acc[0..1][2..3]
    bf16x8 bHi[2][2];
#pragma unroll
    for (int j = 0; j < 2; j++)
#pragma unroll
      for (int kk = 0; kk < 2; kk++) bHi[j][kk] = ldsAB(Bc, br + 32 + j * 16 + lr, kk, lg);
    if (st) stageB_unit(Bt, bRow0, k2, 0, Bn, tid);
    SBAR(); LGKM0();
    __builtin_amdgcn_s_setprio(1);
#pragma unroll
    for (int kk = 0; kk < 2; kk++)
#pragma unroll
      for (int i = 0; i < 2; i++)
#pragma unroll
        for (int j = 0; j < 2; j++)
          acc[i][j + 2] = __builtin_amdgcn_mfma_f32_16x16x32_bf16(aLo[i][kk], bHi[j][kk], acc[i][j + 2], 0, 0, 0);
    __builtin_amdgcn_s_setprio(0);
    SBAR();

    // ---- P3: ds_read A(i=2,3); stage A-unit1(t+2); MFMA acc[2..3][2..3]
    bf16x8 aHi[2][2];
#pragma unroll
    for (int i = 0; i < 2; i++)
#pragma unroll
      for (int kk = 0; kk < 2; kk++) aHi[i][kk] = ldsAB(Ac, ar + 32 + i * 16 + lr, kk, lg);
    if (st) stageA_unit(A, aRow0, k2, 1, An, tid);
    SBAR(); LGKM0();
    __builtin_amdgcn_s_setprio(1);
#pragma unroll
    for (int kk = 0; kk < 2; kk++)
#pragma unroll
      for (int i = 0; i < 2; i++)
#pragma unroll
        for (int j = 0; j < 2; j++)
          acc[i + 2][j + 2] = __builtin_amdgcn_mfma_f32_16x16x32_bf16(aHi[i][kk], bHi[j][kk], acc[i + 2][j + 2], 0, 0, 0);
    __builtin_amdgcn_s_setprio(0);
    SBAR();

    // ---- P4: no ds_read (aHi, bLo in regs); stage B-unit1(t+2); MFMA acc[2..3][0..1];
    //          counted vmcnt (6 steady / 0 at t==14), barrier -> next tile ready
    if (st) stageB_unit(Bt, bRow0, k2, 1, Bn, tid);
    SBAR();
    __builtin_amdgcn_s_setprio(1);
#pragma unroll
    for (int kk = 0; kk < 2; kk++)
#pragma unroll
      for (int i = 0; i < 2; i++)
#pragma unroll
        for (int j = 0; j < 2; j++)
          acc[i + 2][j] = __builtin_amdgcn_mfma_f32_16x16x32_bf16(aHi[i][kk], bLo[j][kk], acc[i + 2][j], 0, 0, 0);
    __builtin_amdgcn_s_setprio(0);
    if (t < 14) { asm volatile("s_waitcnt vmcnt(6)" ::: "memory"); }
    else if (t == 14) { asm volatile("s_waitcnt vmcnt(0)" ::: "memory"); }
    SCHEDB();
    SBAR();

    rs = (rs == 2) ? 0 : rs + 1;
  }

  int crow = aRow0 + wm * 64;
  int ccol = bRow0 + wn * 64;
  if (mode == 0) {   // QKV epilogue: +bias, ->bf16, scatter Q/K [bh][t][d], V -> VT [bh][d][t]
#pragma unroll
    for (int j = 0; j < 4; j++) {
      int col = ccol + j * 16 + lr;
      float bb = bias[col];
      int p = col >> 10, h = (col >> 6) & 15, d = col & 63;
#pragma unroll
      for (int i = 0; i < 4; i++) {
        int row0 = crow + i * 16 + lg * 4;
        int b_ = row0 >> 11, t0 = row0 & 2047;
        if (p == 2) {
          u32x2 pv;
          pv.x = pack2(acc[i][j][0] + bb, acc[i][j][1] + bb);
          pv.y = pack2(acc[i][j][2] + bb, acc[i][j][3] + bb);
          *(u32x2*)&VTb[((size_t)(b_ * 16 + h) * 64 + d) * 2048 + t0] = pv;
        } else {
          u16* dst = (p == 0 ? Qb : Kb);
#pragma unroll
          for (int r = 0; r < 4; r++)
            dst[((size_t)(b_ * 16 + h) * 2048 + (t0 + r)) * 64 + d] = f2bf(acc[i][j][r] + bb);
        }
      }
    }
  } else {           // final projection epilogue: +bias, fp32 out
#pragma unroll
    for (int j = 0; j < 4; j++) {
      int col = ccol + j * 16 + lr;
      float bb = bias[col];
#pragma unroll
      for (int i = 0; i < 4; i++) {
        int row0 = crow + i * 16 + lg * 4;
#pragma unroll
        for (int r = 0; r < 4; r++)
          outF[(size_t)(row0 + r) * 1024 + col] = acc[i][j][r] + bb;
      }
    }
  }
}

// ---------------------------------------------------------------- flash attention (causal, 32x32)
// 2048 blocks of 2 waves; block = one 64-row q-tile t (t=0..31) of one (b,h); iters = t+1.
// Longest-first dispatch + oversubscription gives dynamic load balance with zero column waste.
// Causal mask only on the diagonal iteration. K/V double-buffered in LDS, XOR-swizzled.
DEV void stage_kv128(const u16* __restrict__ Kh, const u16* __restrict__ Vh, int kv0,
                     u16* Ksb, u16* Vsb, int tid) {
#pragma unroll
  for (int j = 0; j < 4; j++) {
    int ci = j * 128 + tid;                 // 512 chunks of 16B = 64 rows x 8 slots
    int row = ci >> 3, slot = ci & 7;
    int ss = slot ^ (row & 7);
    __builtin_amdgcn_global_load_lds(
        (const __attribute__((address_space(1))) void*)(Kh + (size_t)(kv0 + row) * 64 + ss * 8),
        (__attribute__((address_space(3))) void*)(Ksb + ci * 8), 16, 0, 0);
    __builtin_amdgcn_global_load_lds(
        (const __attribute__((address_space(1))) void*)(Vh + (size_t)row * 2048 + kv0 + ss * 8),
        (__attribute__((address_space(3))) void*)(Vsb + ci * 8), 16, 0, 0);
  }
}

__global__ __launch_bounds__(128, 2) void attn_kernel(
    const u16* __restrict__ Qb, const u16* __restrict__ Kb, const u16* __restrict__ VTb,
    u16* __restrict__ cat) {
  __shared__ u16 Ks[2][64 * 64];
  __shared__ u16 Vs[2][64 * 64];
  int bid = blockIdx.x;                 // 2048 = 32 t x 64 bh, longest-first
  int t = 31 - (bid >> 6);              // q-tile index: rows [64t, 64t+64)
  int bh = bid & 63;
  int b = bh >> 4, h = bh & 15;
  int tid = threadIdx.x, wave = tid >> 6, lane = tid & 63;
  int l31 = lane & 31, hi = lane >> 5;
  int qrow = t * 64 + wave * 32 + l31;

  const u16* Qh = Qb + (size_t)bh * 2048 * 64;
  const u16* Kh = Kb + (size_t)bh * 2048 * 64;
  const u16* Vh = VTb + (size_t)bh * 64 * 2048;

  bf16x8 qf[4];                         // B-operand: col=q (lane&31), k = ks*16 + hi*8 + i
#pragma unroll
  for (int ks = 0; ks < 4; ks++)
    qf[ks] = *(const bf16x8*)&Qh[(size_t)qrow * 64 + ks * 16 + hi * 8];

  u32 loff[4];
#pragma unroll
  for (int ks = 0; ks < 4; ks++)
    loff[ks] = (u32)(l31 * 128 + (((ks * 2 + hi) ^ (l31 & 7)) * 16));

  f32x16 o0 = zero16(), o1 = zero16();
  float m_run = -1e30f, l_run = 0.f;
  int iters = t + 1;

  stage_kv128(Kh, Vh, 0, Ks[0], Vs[0], tid);
  __syncthreads();
  int cur = 0;

  for (int kvt = 0; kvt < iters; ++kvt) {
    int kv0 = kvt * 64;
    if (kvt + 1 < iters) stage_kv128(Kh, Vh, kv0 + 64, Ks[cur ^ 1], Vs[cur ^ 1], tid);

    f32x16 s0 = zero16(), s1 = zero16();
    const char* kb = (const char*)&Ks[cur][0];
    __builtin_amdgcn_s_setprio(1);
#pragma unroll
    for (int ks = 0; ks < 4; ks++) {
      bf16x8 k0 = *(const bf16x8*)(kb + loff[ks]);
      bf16x8 k1 = *(const bf16x8*)(kb + loff[ks] + 4096);
      s0 = __builtin_amdgcn_mfma_f32_32x32x16_bf16(k0, qf[ks], s0, 0, 0, 0);
      s1 = __builtin_amdgcn_mfma_f32_32x32x16_bf16(k1, qf[ks], s1, 0, 0, 0);
    }
    __builtin_amdgcn_s_setprio(0);

    if (kvt == t) {
      int relh = qrow - kv0 - 4 * hi;
#pragma unroll
      for (int r = 0; r < 16; r++) {
        int off = (r & 3) + 8 * (r >> 2);
        s0[r] = (off > relh) ? -1e30f : s0[r];
        s1[r] = (off + 32 > relh) ? -1e30f : s1[r];
      }
    }

    float ta = max3f(s0[0], s0[1], s0[2]);
    float tb = max3f(s0[4], s0[5], s0[6]);
    float tc = max3f(s0[8], s0[9], s0[10]);
    float td = max3f(s0[12], s0[13], s0[14]);
    ta = max3f(ta, s0[3], s1[0]);
    tb = max3f(tb, s0[7], s1[4]);
    tc = max3f(tc, s0[11], s1[8]);
    td = max3f(td, s0[15], s1[12]);
    ta = max3f(ta, s1[1], s1[2]);
    tb = max3f(tb, s1[5], s1[6]);
    tc = max3f(tc, s1[9], s1[10]);
    td = max3f(td, s1[13], s1[14]);
    ta = max3f(ta, s1[3], tb);
    tc = max3f(tc, s1[7], td);
    float tmax = max3f(ta, tc, s1[11]);
    tmax = fmaxf(tmax, s1[15]);
    tmax = fmaxf(tmax, __shfl_xor(tmax, 32));
    float corr = 1.f;
    if (!__all(tmax <= m_run + 8.f)) {
      float m_new = fmaxf(m_run, tmax);
      corr = exp2_hw(m_run - m_new);
      o0 = o0 * corr;
      o1 = o1 * corr;
      m_run = m_new;
    }
    float t0 = 0.f, t1 = 0.f, t2 = 0.f, t3 = 0.f;
#pragma unroll
    for (int j = 0; j < 4; j++) {
      float p00 = exp2_hw(s0[j * 4 + 0] - m_run); s0[j * 4 + 0] = p00; t0 += p00;
      float p01 = exp2_hw(s0[j * 4 + 1] - m_run); s0[j * 4 + 1] = p01; t1 += p01;
      float p02 = exp2_hw(s0[j * 4 + 2] - m_run); s0[j * 4 + 2] = p02; t2 += p02;
      float p03 = exp2_hw(s0[j * 4 + 3] - m_run); s0[j * 4 + 3] = p03; t3 += p03;
      float p10 = exp2_hw(s1[j * 4 + 0] - m_run); s1[j * 4 + 0] = p10; t0 += p10;
      float p11 = exp2_hw(s1[j * 4 + 1] - m_run); s1[j * 4 + 1] = p11; t1 += p11;
      float p12 = exp2_hw(s1[j * 4 + 2] - m_run); s1[j * 4 + 2] = p12; t2 += p12;
      float p13 = exp2_hw(s1[j * 4 + 3] - m_run); s1[j * 4 + 3] = p13; t3 += p13;
    }
    float ts = (t0 + t1) + (t2 + t3);
    ts += __shfl_xor(ts, 32);
    l_run = l_run * corr + ts;

    const char* vb = (const char*)&Vs[cur][0];
    __builtin_amdgcn_s_setprio(1);
#pragma unroll
    for (int ks = 0; ks < 4; ks++) {
      const f32x16& sb = (ks < 2) ? s0 : s1;
      int g2 = (ks & 1) * 8;
      u32 a  = cvtpk_bf16(sb[g2 + 0], sb[g2 + 1]);
      u32 c  = cvtpk_bf16(sb[g2 + 2], sb[g2 + 3]);
      u32 bb = cvtpk_bf16(sb[g2 + 4], sb[g2 + 5]);
      u32 d  = cvtpk_bf16(sb[g2 + 6], sb[g2 + 7]);
      pl32swap(a, bb);
      pl32swap(c, d);
      u32x4 wv; wv.x = a; wv.y = c; wv.z = bb; wv.w = d;
      bf16x8 pf = __builtin_bit_cast(bf16x8, wv);
      bf16x8 v0 = *(const bf16x8*)(vb + loff[ks]);
      bf16x8 v1 = *(const bf16x8*)(vb + loff[ks] + 4096);
      o0 = __builtin_amdgcn_mfma_f32_32x32x16_bf16(v0, pf, o0, 0, 0, 0);
      o1 = __builtin_amdgcn_mfma_f32_32x32x16_bf16(v1, pf, o1, 0, 0, 0);
    }
    __builtin_amdgcn_s_setprio(0);

    __syncthreads();
    cur ^= 1;
  }

  float li = 1.0f / l_run;
#pragma unroll
  for (int m = 0; m < 8; m++) {
    int dbase = 2 * (m & 1) + 8 * (m >> 1) + 4 * hi;
    u32 w0 = cvtpk_bf16(o0[2 * m] * li, o0[2 * m + 1] * li);
    u32 w1 = cvtpk_bf16(o1[2 * m] * li, o1[2 * m + 1] * li);
    *(u32*)&cat[(size_t)(b * 2048 + qrow) * 1024 + h * 64 + dbase] = w0;
    *(u32*)&cat[(size_t)(b * 2048 + qrow) * 1024 + h * 64 + 32 + dbase] = w1;
  }
}

// ---------------------------------------------------------------- launch
extern "C" void kernel_launch(void* const* d_in, const int* in_sizes, int n_in,
                              void* d_out, int out_size, void* d_ws, size_t ws_size,
                              hipStream_t stream) {
  const float* x  = (const float*)d_in[0];
  const float* Wq = (const float*)d_in[1];
  const float* bq = (const float*)d_in[2];
  const float* Wk = (const float*)d_in[3];
  const float* bk = (const float*)d_in[4];
  const float* Wv = (const float*)d_in[5];
  const float* bv = (const float*)d_in[6];
  const float* Wp = (const float*)d_in[7];
  const float* bp = (const float*)d_in[8];

  char* w = (char*)d_ws;
  u16* xbf    = (u16*)w;                 w += (size_t)8192 * 1024 * 2;
  u16* wqkvT  = (u16*)w;                 w += (size_t)3072 * 1024 * 2;
  u16* wpT    = (u16*)w;                 w += (size_t)1024 * 1024 * 2;
  float* bqkv = (float*)w;               w += (size_t)3072 * 4;
  u16* Qb     = (u16*)w;                 w += (size_t)64 * 2048 * 64 * 2;
  u16* Kb     = (u16*)w;                 w += (size_t)64 * 2048 * 64 * 2;
  u16* VTb    = (u16*)w;                 w += (size_t)64 * 64 * 2048 * 2;
  u16* cat    = (u16*)w;                 w += (size_t)8192 * 1024 * 2;

  prep_x_kernel<<<4096, 256, 0, stream>>>(x, bq, bk, bv, xbf, bqkv);
  prep_w_kernel<<<1024, 256, 0, stream>>>(Wq, Wk, Wv, Wp, wqkvT, wpT);
  gemm256_kernel<<<768, 512, 0, stream>>>(xbf, wqkvT, bqkv, 24, 0, Qb, Kb, VTb, nullptr);
  attn_kernel<<<2048, 128, 0, stream>>>(Qb, Kb, VTb, cat);
  gemm256_kernel<<<256, 512, 0, stream>>>(cat, wpT, bp, 8, 1, nullptr, nullptr, nullptr, (float*)d_out);
}

// Round 7
// 161.704 us; speedup vs baseline: 1.4604x; 1.0266x over previous
//
#include <hip/hip_runtime.h>

// MHA fused forward for B=4,T=2048,E=1024,H=16,D=64 on gfx950.
// prep (bf16 cast + weight transpose, QK-scale folded into Wq) -> GEMM1 (QKV, 2-phase x16-MFMA
// 256x128 tri-buffer) -> flash attn (32x32 MFMA, longest-first blocks, T12) -> GEMM2 (same GEMM).

typedef __attribute__((ext_vector_type(8))) __bf16 bf16x8;
typedef __attribute__((ext_vector_type(4))) float f32x4;
typedef __attribute__((ext_vector_type(16))) float f32x16;
typedef __attribute__((ext_vector_type(4))) unsigned int u32x4;
typedef __attribute__((ext_vector_type(2))) unsigned int u32x2;
typedef unsigned short u16;
typedef unsigned int u32;

#define DEV __device__ __forceinline__

#define QK_SCALE 0.18033688011112042f   // 0.125 * log2(e) : folded into Wq/bq

DEV u16 f2bf(float f) {          // round-to-nearest-even f32 -> bf16 (inputs never NaN)
  u32 u = __builtin_bit_cast(u32, f);
  u += 0x7fffu + ((u >> 16) & 1u);
  return (u16)(u >> 16);
}
DEV u32 pack2(float a, float b) { return (u32)f2bf(a) | ((u32)f2bf(b) << 16); }

DEV float exp2_hw(float x) { float r; asm("v_exp_f32 %0, %1" : "=v"(r) : "v"(x)); return r; }
DEV u32 cvtpk_bf16(float lo, float hi) {
  u32 r; asm("v_cvt_pk_bf16_f32 %0, %1, %2" : "=v"(r) : "v"(lo), "v"(hi)); return r;
}
DEV void pl32swap(u32& a, u32& b) { asm("v_permlane32_swap_b32 %0, %1" : "+v"(a), "+v"(b)); }
DEV float max3f(float a, float b, float c) {
  float r; asm("v_max3_f32 %0, %1, %2, %3" : "=v"(r) : "v"(a), "v"(b), "v"(c)); return r;
}

DEV f32x16 zero16() { f32x16 z;
#pragma unroll
  for (int i = 0; i < 16; i++) z[i] = 0.f;
  return z; }

DEV void gll16(const u16* g, u16* l) {
  __builtin_amdgcn_global_load_lds((const __attribute__((address_space(1))) void*)g,
                                   (__attribute__((address_space(3))) void*)l, 16, 0, 0);
}

#define SCHEDB() __builtin_amdgcn_sched_barrier(0)
#define SBAR()   do { __builtin_amdgcn_s_barrier(); SCHEDB(); } while (0)
#define LGKM0()  do { asm volatile("s_waitcnt lgkmcnt(0)" ::: "memory"); SCHEDB(); } while (0)

// ---------------------------------------------------------------- prep: x->bf16, bias concat
__global__ __launch_bounds__(256) void prep_x_kernel(
    const float* __restrict__ x, const float* __restrict__ bq, const float* __restrict__ bk,
    const float* __restrict__ bv, u16* __restrict__ xbf, float* __restrict__ bqkv) {
  int gid = blockIdx.x * 256 + threadIdx.x;
  if (gid < 3072) {
    float v = (gid < 1024) ? bq[gid] * QK_SCALE : (gid < 2048 ? bk[gid - 1024] : bv[gid - 2048]);
    bqkv[gid] = v;
  }
  const float4* xv = (const float4*)x;
  float4 f0 = xv[(size_t)gid * 2];
  float4 f1 = xv[(size_t)gid * 2 + 1];
  u32x4 st;
  st.x = pack2(f0.x, f0.y); st.y = pack2(f0.z, f0.w);
  st.z = pack2(f1.x, f1.y); st.w = pack2(f1.z, f1.w);
  *(u32x4*)&xbf[(size_t)gid * 8] = st;
}

// ---------------------------------------------------------------- prep: weight transposes to B^T bf16
__global__ __launch_bounds__(256) void prep_w_kernel(
    const float* __restrict__ Wq, const float* __restrict__ Wk, const float* __restrict__ Wv,
    const float* __restrict__ Wp, u16* __restrict__ wqkvT, u16* __restrict__ wpT) {
  __shared__ float t[64][65];
  int bid = blockIdx.x, tid = threadIdx.x;
  int r0 = tid >> 6, c = tid & 63;
  if (bid < 768) {
    int p = bid >> 8, rem = bid & 255, h = rem >> 4, et = rem & 15;
    float sc = (p == 0) ? QK_SCALE : 1.0f;
    const float* src = (p == 0 ? Wq : (p == 1 ? Wk : Wv)) + ((size_t)h * 1024 + et * 64) * 64;
#pragma unroll
    for (int i = 0; i < 16; i++) { int e = r0 + i * 4; t[e][c] = src[(size_t)e * 64 + c]; }
    __syncthreads();
    u16* dst = wqkvT + ((size_t)p * 1024 + h * 64) * 1024 + et * 64;
#pragma unroll
    for (int i = 0; i < 16; i++) { int d = r0 + i * 4; dst[(size_t)d * 1024 + c] = f2bf(t[c][d] * sc); }
  } else {
    int b2 = bid - 768, rt = b2 >> 4, ct = b2 & 15;
#pragma unroll
    for (int i = 0; i < 16; i++) { int e = r0 + i * 4; t[e][c] = Wp[(size_t)(rt * 64 + e) * 1024 + ct * 64 + c]; }
    __syncthreads();
#pragma unroll
    for (int i = 0; i < 16; i++) { int f = r0 + i * 4; wpT[(size_t)(ct * 64 + f) * 1024 + rt * 64 + c] = f2bf(t[c][f]); }
  }
}

// ---------------------------------------------------------------- GEMM 256x128 tile, 2-phase x 16-MFMA
// BM=256, BN=128, BK=64, 512 thr (8 waves 4Mx2N, 64x64/wave). Triple-buffered K-tiles
// (prefetch distance 2) -> steady-state wait = vmcnt(6) once per K-tile, never 0.
// 2 phases/K-tile: P1 {12 ds_read (A all + B lo) || stage A(t+2) -> lgkm(8) -> bar -> lgkm0 ->
// 16 MFMA -> bar}; P2 {4 ds_read (B hi) || stage B(t+2) -> bar -> lgkm0 -> 16 MFMA ->
// vmcnt(6) -> bar}. XOR swizzle slot^=(row&7) both sides (rule #21).
#define SLOT_U16 24576            // A tile 256x64 (16384) + B tile 128x64 (8192)

DEV void stageA_unit(const u16* __restrict__ Asrc, int row0, int k0, int h, u16* An, int tid) {
#pragma unroll
  for (int jj = 0; jj < 2; jj++) {
    int idx = jj * 512 + tid;                 // 1024 chunks of 16B = 128 rows x 8 slots
    int row = h * 128 + (idx >> 3), slot = idx & 7;
    int ss = slot ^ (row & 7);
    gll16(Asrc + (size_t)(row0 + row) * 1024 + k0 + ss * 8, An + (size_t)row * 64 + slot * 8);
  }
}
DEV void stageB_unit(const u16* __restrict__ Bsrc, int row0, int k0, int h, u16* Bn, int tid) {
  int idx = tid;                              // 512 chunks = 64 rows x 8 slots
  int row = h * 64 + (idx >> 3), slot = idx & 7;
  int ss = slot ^ (row & 7);
  gll16(Bsrc + (size_t)(row0 + row) * 1024 + k0 + ss * 8, Bn + (size_t)row * 64 + slot * 8);
}

DEV bf16x8 ldsAB(const u16* base, int row, int kk, int lg) {
  return *(const bf16x8*)&base[row * 64 + (((lg + kk * 4) ^ (row & 7)) * 8)];
}

__global__ __launch_bounds__(512, 2) void gemm256_kernel(
    const u16* __restrict__ A, const u16* __restrict__ Bt, const float* __restrict__ bias,
    int tilesN, int mode, u16* __restrict__ Qb, u16* __restrict__ Kb, u16* __restrict__ VTb,
    float* __restrict__ outF) {
  __shared__ u16 lds[3 * SLOT_U16];           // 144 KiB
  int nwg = gridDim.x;
  int bid = blockIdx.x;
  int swz = (bid % 8) * (nwg / 8) + bid / 8;  // XCD-contiguous (nwg % 8 == 0)
  int bm = swz / tilesN, bn = swz % tilesN;
  int tid = threadIdx.x;
  int lane = tid & 63, wave = tid >> 6;
  int wm = wave >> 1, wn = wave & 1;          // 4M x 2N
  int lr = lane & 15, lg = lane >> 4;
  int aRow0 = bm * 256, bRow0 = bn * 128;
  int ar = wm * 64, br = wn * 64;             // wave's A-row / B-row (=N col) base in tile

  f32x4 acc[4][4];
#pragma unroll
  for (int i = 0; i < 4; i++)
#pragma unroll
    for (int j = 0; j < 4; j++) acc[i][j] = f32x4{0.f, 0.f, 0.f, 0.f};

  // prologue: stage tiles 0 and 1 (6 insts each)
#pragma unroll
  for (int pt = 0; pt < 2; pt++) {
    u16* As = lds + pt * SLOT_U16;
    stageA_unit(A, aRow0, pt * 64, 0, As, tid);
    stageA_unit(A, aRow0, pt * 64, 1, As, tid);
    stageB_unit(Bt, bRow0, pt * 64, 0, As + 16384, tid);
    stageB_unit(Bt, bRow0, pt * 64, 1, As + 16384, tid);
  }
  asm volatile("s_waitcnt vmcnt(6)" ::: "memory");   // tile0 landed; tile1 in flight
  SCHEDB();
  SBAR();

  int rs = 0;                                 // read slot = t % 3
  for (int t = 0; t < 16; ++t) {
    u16* Ac = lds + rs * SLOT_U16;
    u16* Bc = Ac + 16384;
    int ws = rs + 2; if (ws >= 3) ws -= 3;    // write slot = (t+2) % 3
    u16* An = lds + ws * SLOT_U16;
    u16* Bn = An + 16384;
    int k2 = (t + 2) * 64;
    bool st = (t + 2) < 16;

    // ---- P1: ds_read all A-frags (8) + B lo (4); stage A-units(t+2); 16 MFMA acc[*][0..1]
    bf16x8 aF[4][2], bLo[2][2];
#pragma unroll
    for (int i = 0; i < 4; i++)
#pragma unroll
      for (int kk = 0; kk < 2; kk++) aF[i][kk] = ldsAB(Ac, ar + i * 16 + lr, kk, lg);
#pragma unroll
    for (int j = 0; j < 2; j++)
#pragma unroll
      for (int kk = 0; kk < 2; kk++) bLo[j][kk] = ldsAB(Bc, br + j * 16 + lr, kk, lg);
    if (st) {
      stageA_unit(A, aRow0, k2, 0, An, tid);
      stageA_unit(A, aRow0, k2, 1, An, tid);
    }
    asm volatile("s_waitcnt lgkmcnt(8)" ::: "memory");  // early-drain first 4 reads
    SCHEDB();
    SBAR(); LGKM0();
    __builtin_amdgcn_s_setprio(1);
#pragma unroll
    for (int kk = 0; kk < 2; kk++)
#pragma unroll
      for (int i = 0; i < 4; i++)
#pragma unroll
        for (int j = 0; j < 2; j++)
          acc[i][j] = __builtin_amdgcn_mfma_f32_16x16x32_bf16(aF[i][kk], bLo[j][kk], acc[i][j], 0, 0, 0);
    __builtin_amdgcn_s_setprio(0);
    SBAR();

    // ---- P2: ds_read B hi (4); stage B-units(t+2); 16 MFMA acc[*][2..3]; counted vmcnt
    bf16x8 bHi[2][2];
#pragma unroll
    for (int j = 0; j < 2; j++)
#pragma unroll
      for (int kk = 0; kk < 2; kk++) bHi[j][kk] = ldsAB(Bc, br + 32 + j * 16 + lr, kk, lg);
    if (st) {
      stageB_unit(Bt, bRow0, k2, 0, Bn, tid);
      stageB_unit(Bt, bRow0, k2, 1, Bn, tid);
    }
    SBAR(); LGKM0();
    __builtin_amdgcn_s_setprio(1);
#pragma unroll
    for (int kk = 0; kk < 2; kk++)
#pragma unroll
      for (int i = 0; i < 4; i++)
#pragma unroll
        for (int j = 0; j < 2; j++)
          acc[i][j + 2] = __builtin_amdgcn_mfma_f32_16x16x32_bf16(aF[i][kk], bHi[j][kk], acc[i][j + 2], 0, 0, 0);
    __builtin_amdgcn_s_setprio(0);
    if (t < 14) { asm volatile("s_waitcnt vmcnt(6)" ::: "memory"); }
    else if (t == 14) { asm volatile("s_waitcnt vmcnt(0)" ::: "memory"); }
    SCHEDB();
    SBAR();

    rs = (rs == 2) ? 0 : rs + 1;
  }

  int crow = aRow0 + wm * 64;
  int ccol = bRow0 + wn * 64;
  if (mode == 0) {   // QKV epilogue: +bias, ->bf16, scatter Q/K [bh][t][d], V -> VT [bh][d][t]
#pragma unroll
    for (int j = 0; j < 4; j++) {
      int col = ccol + j * 16 + lr;
      float bb = bias[col];
      int p = col >> 10, h = (col >> 6) & 15, d = col & 63;
#pragma unroll
      for (int i = 0; i < 4; i++) {
        int row0 = crow + i * 16 + lg * 4;
        int b_ = row0 >> 11, t0 = row0 & 2047;
        if (p == 2) {
          u32x2 pv;
          pv.x = pack2(acc[i][j][0] + bb, acc[i][j][1] + bb);
          pv.y = pack2(acc[i][j][2] + bb, acc[i][j][3] + bb);
          *(u32x2*)&VTb[((size_t)(b_ * 16 + h) * 64 + d) * 2048 + t0] = pv;
        } else {
          u16* dst = (p == 0 ? Qb : Kb);
#pragma unroll
          for (int r = 0; r < 4; r++)
            dst[((size_t)(b_ * 16 + h) * 2048 + (t0 + r)) * 64 + d] = f2bf(acc[i][j][r] + bb);
        }
      }
    }
  } else {           // final projection epilogue: +bias, fp32 out
#pragma unroll
    for (int j = 0; j < 4; j++) {
      int col = ccol + j * 16 + lr;
      float bb = bias[col];
#pragma unroll
      for (int i = 0; i < 4; i++) {
        int row0 = crow + i * 16 + lg * 4;
#pragma unroll
        for (int r = 0; r < 4; r++)
          outF[(size_t)(row0 + r) * 1024 + col] = acc[i][j][r] + bb;
      }
    }
  }
}

// ---------------------------------------------------------------- flash attention (causal, 32x32)
// 2048 blocks of 2 waves; block = one 64-row q-tile t (t=0..31) of one (b,h); iters = t+1.
// Longest-first dispatch + oversubscription gives dynamic load balance with zero column waste.
// Causal mask only on the diagonal iteration. K/V double-buffered in LDS, XOR-swizzled.
DEV void stage_kv128(const u16* __restrict__ Kh, const u16* __restrict__ Vh, int kv0,
                     u16* Ksb, u16* Vsb, int tid) {
#pragma unroll
  for (int j = 0; j < 4; j++) {
    int ci = j * 128 + tid;                 // 512 chunks of 16B = 64 rows x 8 slots
    int row = ci >> 3, slot = ci & 7;
    int ss = slot ^ (row & 7);
    __builtin_amdgcn_global_load_lds(
        (const __attribute__((address_space(1))) void*)(Kh + (size_t)(kv0 + row) * 64 + ss * 8),
        (__attribute__((address_space(3))) void*)(Ksb + ci * 8), 16, 0, 0);
    __builtin_amdgcn_global_load_lds(
        (const __attribute__((address_space(1))) void*)(Vh + (size_t)row * 2048 + kv0 + ss * 8),
        (__attribute__((address_space(3))) void*)(Vsb + ci * 8), 16, 0, 0);
  }
}

__global__ __launch_bounds__(128, 2) void attn_kernel(
    const u16* __restrict__ Qb, const u16* __restrict__ Kb, const u16* __restrict__ VTb,
    u16* __restrict__ cat) {
  __shared__ u16 Ks[2][64 * 64];
  __shared__ u16 Vs[2][64 * 64];
  int bid = blockIdx.x;                 // 2048 = 32 t x 64 bh, longest-first
  int t = 31 - (bid >> 6);              // q-tile index: rows [64t, 64t+64)
  int bh = bid & 63;
  int b = bh >> 4, h = bh & 15;
  int tid = threadIdx.x, wave = tid >> 6, lane = tid & 63;
  int l31 = lane & 31, hi = lane >> 5;
  int qrow = t * 64 + wave * 32 + l31;

  const u16* Qh = Qb + (size_t)bh * 2048 * 64;
  const u16* Kh = Kb + (size_t)bh * 2048 * 64;
  const u16* Vh = VTb + (size_t)bh * 64 * 2048;

  bf16x8 qf[4];                         // B-operand: col=q (lane&31), k = ks*16 + hi*8 + i
#pragma unroll
  for (int ks = 0; ks < 4; ks++)
    qf[ks] = *(const bf16x8*)&Qh[(size_t)qrow * 64 + ks * 16 + hi * 8];

  u32 loff[4];
#pragma unroll
  for (int ks = 0; ks < 4; ks++)
    loff[ks] = (u32)(l31 * 128 + (((ks * 2 + hi) ^ (l31 & 7)) * 16));

  f32x16 o0 = zero16(), o1 = zero16();
  float m_run = -1e30f, l_run = 0.f;
  int iters = t + 1;

  stage_kv128(Kh, Vh, 0, Ks[0], Vs[0], tid);
  __syncthreads();
  int cur = 0;

  for (int kvt = 0; kvt < iters; ++kvt) {
    int kv0 = kvt * 64;
    if (kvt + 1 < iters) stage_kv128(Kh, Vh, kv0 + 64, Ks[cur ^ 1], Vs[cur ^ 1], tid);

    f32x16 s0 = zero16(), s1 = zero16();
    const char* kb = (const char*)&Ks[cur][0];
    __builtin_amdgcn_s_setprio(1);
#pragma unroll
    for (int ks = 0; ks < 4; ks++) {
      bf16x8 k0 = *(const bf16x8*)(kb + loff[ks]);
      bf16x8 k1 = *(const bf16x8*)(kb + loff[ks] + 4096);
      s0 = __builtin_amdgcn_mfma_f32_32x32x16_bf16(k0, qf[ks], s0, 0, 0, 0);
      s1 = __builtin_amdgcn_mfma_f32_32x32x16_bf16(k1, qf[ks], s1, 0, 0, 0);
    }
    __builtin_amdgcn_s_setprio(0);

    if (kvt == t) {
      int relh = qrow - kv0 - 4 * hi;
#pragma unroll
      for (int r = 0; r < 16; r++) {
        int off = (r & 3) + 8 * (r >> 2);
        s0[r] = (off > relh) ? -1e30f : s0[r];
        s1[r] = (off + 32 > relh) ? -1e30f : s1[r];
      }
    }

    float ta = max3f(s0[0], s0[1], s0[2]);
    float tb = max3f(s0[4], s0[5], s0[6]);
    float tc = max3f(s0[8], s0[9], s0[10]);
    float td = max3f(s0[12], s0[13], s0[14]);
    ta = max3f(ta, s0[3], s1[0]);
    tb = max3f(tb, s0[7], s1[4]);
    tc = max3f(tc, s0[11], s1[8]);
    td = max3f(td, s0[15], s1[12]);
    ta = max3f(ta, s1[1], s1[2]);
    tb = max3f(tb, s1[5], s1[6]);
    tc = max3f(tc, s1[9], s1[10]);
    td = max3f(td, s1[13], s1[14]);
    ta = max3f(ta, s1[3], tb);
    tc = max3f(tc, s1[7], td);
    float tmax = max3f(ta, tc, s1[11]);
    tmax = fmaxf(tmax, s1[15]);
    tmax = fmaxf(tmax, __shfl_xor(tmax, 32));
    float corr = 1.f;
    if (!__all(tmax <= m_run + 8.f)) {
      float m_new = fmaxf(m_run, tmax);
      corr = exp2_hw(m_run - m_new);
      o0 = o0 * corr;
      o1 = o1 * corr;
      m_run = m_new;
    }
    float t0 = 0.f, t1 = 0.f, t2 = 0.f, t3 = 0.f;
#pragma unroll
    for (int j = 0; j < 4; j++) {
      float p00 = exp2_hw(s0[j * 4 + 0] - m_run); s0[j * 4 + 0] = p00; t0 += p00;
      float p01 = exp2_hw(s0[j * 4 + 1] - m_run); s0[j * 4 + 1] = p01; t1 += p01;
      float p02 = exp2_hw(s0[j * 4 + 2] - m_run); s0[j * 4 + 2] = p02; t2 += p02;
      float p03 = exp2_hw(s0[j * 4 + 3] - m_run); s0[j * 4 + 3] = p03; t3 += p03;
      float p10 = exp2_hw(s1[j * 4 + 0] - m_run); s1[j * 4 + 0] = p10; t0 += p10;
      float p11 = exp2_hw(s1[j * 4 + 1] - m_run); s1[j * 4 + 1] = p11; t1 += p11;
      float p12 = exp2_hw(s1[j * 4 + 2] - m_run); s1[j * 4 + 2] = p12; t2 += p12;
      float p13 = exp2_hw(s1[j * 4 + 3] - m_run); s1[j * 4 + 3] = p13; t3 += p13;
    }
    float ts = (t0 + t1) + (t2 + t3);
    ts += __shfl_xor(ts, 32);
    l_run = l_run * corr + ts;

    const char* vb = (const char*)&Vs[cur][0];
    __builtin_amdgcn_s_setprio(1);
#pragma unroll
    for (int ks = 0; ks < 4; ks++) {
      const f32x16& sb = (ks < 2) ? s0 : s1;
      int g2 = (ks & 1) * 8;
      u32 a  = cvtpk_bf16(sb[g2 + 0], sb[g2 + 1]);
      u32 c  = cvtpk_bf16(sb[g2 + 2], sb[g2 + 3]);
      u32 bb = cvtpk_bf16(sb[g2 + 4], sb[g2 + 5]);
      u32 d  = cvtpk_bf16(sb[g2 + 6], sb[g2 + 7]);
      pl32swap(a, bb);
      pl32swap(c, d);
      u32x4 wv; wv.x = a; wv.y = c; wv.z = bb; wv.w = d;
      bf16x8 pf = __builtin_bit_cast(bf16x8, wv);
      bf16x8 v0 = *(const bf16x8*)(vb + loff[ks]);
      bf16x8 v1 = *(const bf16x8*)(vb + loff[ks] + 4096);
      o0 = __builtin_amdgcn_mfma_f32_32x32x16_bf16(v0, pf, o0, 0, 0, 0);
      o1 = __builtin_amdgcn_mfma_f32_32x32x16_bf16(v1, pf, o1, 0, 0, 0);
    }
    __builtin_amdgcn_s_setprio(0);

    __syncthreads();
    cur ^= 1;
  }

  float li = 1.0f / l_run;
#pragma unroll
  for (int m = 0; m < 8; m++) {
    int dbase = 2 * (m & 1) + 8 * (m >> 1) + 4 * hi;
    u32 w0 = cvtpk_bf16(o0[2 * m] * li, o0[2 * m + 1] * li);
    u32 w1 = cvtpk_bf16(o1[2 * m] * li, o1[2 * m + 1] * li);
    *(u32*)&cat[(size_t)(b * 2048 + qrow) * 1024 + h * 64 + dbase] = w0;
    *(u32*)&cat[(size_t)(b * 2048 + qrow) * 1024 + h * 64 + 32 + dbase] = w1;
  }
}

// ---------------------------------------------------------------- launch
extern "C" void kernel_launch(void* const* d_in, const int* in_sizes, int n_in,
                              void* d_out, int out_size, void* d_ws, size_t ws_size,
                              hipStream_t stream) {
  const float* x  = (const float*)d_in[0];
  const float* Wq = (const float*)d_in[1];
  const float* bq = (const float*)d_in[2];
  const float* Wk = (const float*)d_in[3];
  const float* bk = (const float*)d_in[4];
  const float* Wv = (const float*)d_in[5];
  const float* bv = (const float*)d_in[6];
  const float* Wp = (const float*)d_in[7];
  const float* bp = (const float*)d_in[8];

  char* w = (char*)d_ws;
  u16* xbf    = (u16*)w;                 w += (size_t)8192 * 1024 * 2;
  u16* wqkvT  = (u16*)w;                 w += (size_t)3072 * 1024 * 2;
  u16* wpT    = (u16*)w;                 w += (size_t)1024 * 1024 * 2;
  float* bqkv = (float*)w;               w += (size_t)3072 * 4;
  u16* Qb     = (u16*)w;                 w += (size_t)64 * 2048 * 64 * 2;
  u16* Kb     = (u16*)w;                 w += (size_t)64 * 2048 * 64 * 2;
  u16* VTb    = (u16*)w;                 w += (size_t)64 * 64 * 2048 * 2;
  u16* cat    = (u16*)w;                 w += (size_t)8192 * 1024 * 2;

  prep_x_kernel<<<4096, 256, 0, stream>>>(x, bq, bk, bv, xbf, bqkv);
  prep_w_kernel<<<1024, 256, 0, stream>>>(Wq, Wk, Wv, Wp, wqkvT, wpT);
  gemm256_kernel<<<768, 512, 0, stream>>>(xbf, wqkvT, bqkv, 24, 0, Qb, Kb, VTb, nullptr);
  attn_kernel<<<2048, 128, 0, stream>>>(Qb, Kb, VTb, cat);
  gemm256_kernel<<<256, 512, 0, stream>>>(cat, wpT, bp, 8, 1, nullptr, nullptr, nullptr, (float*)d_out);
}